// Round 1
// baseline (438.931 us; speedup 1.0000x reference)
//
#include <hip/hip_runtime.h>
#include <math.h>

#define SSM_N 64
#define SSM_H 1024
#define SSM_L 2048
#define SSM_B 8
#define FFTN 2048
#define FFTLOG 11
#define NT 256
#define KFS 2052   // row stride (float2) for Kf, 2049 used

__device__ __forceinline__ float2 cmulf(float2 a, float2 b){ return make_float2(a.x*b.x - a.y*b.y, a.x*b.y + a.y*b.x); }
__device__ __forceinline__ float2 caddf(float2 a, float2 b){ return make_float2(a.x+b.x, a.y+b.y); }
__device__ __forceinline__ float2 csubf(float2 a, float2 b){ return make_float2(a.x-b.x, a.y-b.y); }
__device__ __forceinline__ float2 cconjf(float2 a){ return make_float2(a.x, -a.y); }

// Stockham radix-2 DIF, 2048-pt, 256 threads, natural-order in/out.
// tw[j] = exp(-2*pi*i*j/2048), j<1024. inverse => conj twiddles (no 1/N scale).
// Returns pointer to buffer holding the result (one of a/b).
__device__ float2* fft2048(float2* a, float2* b, const float2* tw, bool inverse, int tid){
  float2* src = a; float2* dst = b;
  for (int t = 0; t < FFTLOG; ++t) {
    int s = 1 << t;
    __syncthreads();
    #pragma unroll
    for (int i = 0; i < FFTN/2/NT; ++i) {
      int idx = tid + i*NT;
      float2 u = src[idx];
      float2 v = src[idx + FFTN/2];
      float2 w = tw[(idx >> t) << t];
      if (inverse) w.y = -w.y;
      int d0 = (idx & (s-1)) + ((idx >> t) << (t+1));
      dst[d0]     = caddf(u, v);
      dst[d0 + s] = cmulf(csubf(u, v), w);
    }
    float2* tmp = src; src = dst; dst = tmp;
  }
  __syncthreads();
  return src;
}

// Stage 1a: cden (transposed to (N,L) for coalesced reads), f2 = 2/(1+z),
// fac = k10/(1+k11). fp64 internally (l = L/2 is near-singular).
__global__ __launch_bounds__(256) void kernel_cden(
    const float* __restrict__ B_re, const float* __restrict__ B_im,
    const float* __restrict__ P_re, const float* __restrict__ P_im,
    const float* __restrict__ Q_re, const float* __restrict__ Q_im,
    const float* __restrict__ diag_re, const float* __restrict__ diag_im,
    const float* __restrict__ step,
    float2* __restrict__ cdenT, float2* __restrict__ f2v, float2* __restrict__ facv)
{
  int l = blockIdx.x * blockDim.x + threadIdx.x;
  if (l >= SSM_L) return;
  double stepc = (double)step[0]; if (stepc < 1e-6) stepc = 1e-6;
  double ang = -2.0 * 3.14159265358979323846 * (double)l / (double)SSM_L;
  double zr = cos(ang), zi = sin(ang);
  double dr = 1.0 + zr, di = zi;
  double nr = 1.0 - zr, ni = -zi;
  double den = dr*dr + di*di;
  double i2s = 2.0 / stepc;
  double gr = i2s * (nr*dr + ni*di) / den;
  double gi = i2s * (ni*dr - nr*di) / den;
  f2v[l] = make_float2((float)(2.0*dr/den), (float)(-2.0*di/den));
  double k10r=0.0, k10i=0.0, k11r=0.0, k11i=0.0;
  for (int n = 0; n < SSM_N; ++n) {
    double ar = gr - (double)diag_re[n];
    double ai = gi - (double)diag_im[n];
    double d2 = ar*ar + ai*ai;
    double cr = ar/d2, ci = -ai/d2;
    cdenT[n*SSM_L + l] = make_float2((float)cr, (float)ci);
    double qr = (double)Q_re[n], qi = (double)Q_im[n];
    double br = (double)B_re[n], bi = (double)B_im[n];
    double pr = (double)P_re[n], pi = (double)P_im[n];
    double qbr = qr*br - qi*bi, qbi = qr*bi + qi*br;
    double qpr = qr*pr - qi*pi, qpi = qr*pi + qi*pr;
    k10r += qbr*cr - qbi*ci; k10i += qbr*ci + qbi*cr;
    k11r += qpr*cr - qpi*ci; k11i += qpr*ci + qpi*cr;
  }
  double er = 1.0 + k11r, ei = k11i;
  double ed = er*er + ei*ei;
  facv[l] = make_float2((float)((k10r*er + k10i*ei)/ed), (float)((k10i*er - k10r*ei)/ed));
}

// Stage 1b: per channel h: at_roots -> ifft -> K -> rfft4096 (packed) -> Kf row.
__global__ __launch_bounds__(256) void kernel_khat(
    const float* __restrict__ C_re, const float* __restrict__ C_im,
    const float* __restrict__ B_re, const float* __restrict__ B_im,
    const float* __restrict__ P_re, const float* __restrict__ P_im,
    const float2* __restrict__ cdenT,
    const float2* __restrict__ f2v, const float2* __restrict__ facv,
    float2* __restrict__ Kf)
{
  __shared__ float2 bufA[FFTN];
  __shared__ float2 bufB[FFTN];
  __shared__ float2 tw[FFTN/2];
  __shared__ float2 CBs[SSM_N];
  __shared__ float2 CPs[SSM_N];
  int tid = threadIdx.x;
  int h = blockIdx.x;
  for (int j = tid; j < FFTN/2; j += NT) {
    float s, c;
    sincosf(-6.2831853071795864769f * (float)j / (float)FFTN, &s, &c);
    tw[j] = make_float2(c, s);
  }
  if (tid < SSM_N) {
    float2 cc = make_float2(C_re[h*SSM_N + tid], C_im[h*SSM_N + tid]);
    CBs[tid] = cmulf(cc, make_float2(B_re[tid], B_im[tid]));
    CPs[tid] = cmulf(cc, make_float2(P_re[tid], P_im[tid]));
  }
  __syncthreads();
  float2 k00[8], k01[8];
  #pragma unroll
  for (int i = 0; i < 8; ++i) { k00[i] = make_float2(0.f,0.f); k01[i] = make_float2(0.f,0.f); }
  for (int n = 0; n < SSM_N; ++n) {
    float2 cb = CBs[n], cp = CPs[n];
    #pragma unroll
    for (int i = 0; i < 8; ++i) {
      float2 cd = cdenT[n*SSM_L + tid + i*NT];
      k00[i] = caddf(k00[i], cmulf(cb, cd));
      k01[i] = caddf(k01[i], cmulf(cp, cd));
    }
  }
  #pragma unroll
  for (int i = 0; i < 8; ++i) {
    int l = tid + i*NT;
    bufA[l] = cmulf(f2v[l], csubf(k00[i], cmulf(k01[i], facv[l])));
  }
  // K = Re(ifft(at_roots))/N
  float2* z = fft2048(bufA, bufB, tw, true, tid);
  float2* other = (z == bufA) ? bufB : bufA;
  const float scale = 1.0f / (float)FFTN;
  #pragma unroll
  for (int i = 0; i < 8; ++i) {
    int j = tid + i*NT;
    float2 v = make_float2(0.f, 0.f);
    if (j < FFTN/2) v = make_float2(z[2*j].x * scale, z[2*j+1].x * scale);
    other[j] = v;   // packed even/odd of zero-padded K
  }
  float2* C2 = fft2048(other, z, tw, false, tid);
  float2* krow = Kf + (size_t)h * KFS;
  #pragma unroll
  for (int i = 0; i < 4; ++i) {
    int k = tid + i*NT;
    if (k == 0) {
      float2 c0 = C2[0];
      krow[0]       = make_float2(c0.x + c0.y, 0.f);
      krow[FFTN]    = make_float2(c0.x - c0.y, 0.f);
      krow[FFTN/2]  = cconjf(C2[FFTN/2]);
    } else {
      int kk = FFTN - k;
      float2 Ck = C2[k], Ckk = C2[kk];
      float2 E = make_float2(0.5f*(Ck.x + Ckk.x), 0.5f*(Ck.y - Ckk.y));
      float2 O = make_float2(0.5f*(Ck.y + Ckk.y), 0.5f*(Ckk.x - Ck.x));
      float s, c;
      sincosf(-3.14159265358979f * (float)k / (float)FFTN, &s, &c);
      float2 w = make_float2(c, s);
      krow[k]  = caddf(E, cmulf(w, O));
      krow[kk] = caddf(cconjf(E), cmulf(make_float2(-c, s), cconjf(O)));
    }
  }
}

// (B,L,H) -> (B,H,L) tiled transpose
__global__ __launch_bounds__(256) void ktranspose(const float* __restrict__ src, float* __restrict__ dst)
{
  __shared__ float tile[32][33];
  int tx = threadIdx.x & 31, ty = threadIdx.x >> 5;
  int h0 = blockIdx.x * 32, l0 = blockIdx.y * 32, b = blockIdx.z;
  const float* s = src + ((size_t)b*SSM_L + l0)*SSM_H + h0;
  #pragma unroll
  for (int i = 0; i < 4; ++i) { int row = ty + i*8; tile[row][tx] = s[(size_t)row*SSM_H + tx]; }
  __syncthreads();
  float* d = dst + ((size_t)b*SSM_H + h0)*SSM_L + l0;
  #pragma unroll
  for (int i = 0; i < 4; ++i) { int row = ty + i*8; d[(size_t)row*SSM_L + tx] = tile[tx][row]; }
}

// Stage 2: per (b,h) row, in place on rT: rfft4096 (packed) -> *Kf -> irfft4096, keep first L.
__global__ __launch_bounds__(256) void kernel_conv(float* __restrict__ rT, const float2* __restrict__ Kf)
{
  __shared__ float2 bufA[FFTN];
  __shared__ float2 bufB[FFTN];
  __shared__ float2 tw[FFTN/2];
  int tid = threadIdx.x;
  int row = blockIdx.x;
  int h = row & (SSM_H - 1);
  for (int j = tid; j < FFTN/2; j += NT) {
    float s, c;
    sincosf(-6.2831853071795864769f * (float)j / (float)FFTN, &s, &c);
    tw[j] = make_float2(c, s);
  }
  float2* rrow = (float2*)(rT + (size_t)row * SSM_L);
  #pragma unroll
  for (int i = 0; i < 8; ++i) {
    int j = tid + i*NT;
    bufA[j] = (j < SSM_L/2) ? rrow[j] : make_float2(0.f, 0.f);
  }
  float2* C2 = fft2048(bufA, bufB, tw, false, tid);
  float2* other = (C2 == bufA) ? bufB : bufA;
  const float2* krow = Kf + (size_t)h * KFS;
  #pragma unroll
  for (int i = 0; i < 4; ++i) {
    int k = tid + i*NT;
    if (k == 0) {
      float2 c0 = C2[0];
      float F0 = c0.x + c0.y, Fn = c0.x - c0.y;
      float2 K0 = krow[0], Kn = krow[FFTN];
      float2 G0 = make_float2(F0*K0.x, F0*K0.y);
      float2 Gn = make_float2(Fn*Kn.x, Fn*Kn.y);
      float2 Xe = make_float2(0.5f*(G0.x+Gn.x), 0.5f*(G0.y+Gn.y));
      float2 Xo = make_float2(0.5f*(G0.x-Gn.x), 0.5f*(G0.y-Gn.y));
      other[0] = make_float2(Xe.x - Xo.y, Xe.y + Xo.x);
      float2 Gm = cmulf(cconjf(C2[FFTN/2]), krow[FFTN/2]);
      other[FFTN/2] = cconjf(Gm);
    } else {
      int kk = FFTN - k;
      float2 Ck = C2[k], Ckk = C2[kk];
      float2 E = make_float2(0.5f*(Ck.x + Ckk.x), 0.5f*(Ck.y - Ckk.y));
      float2 O = make_float2(0.5f*(Ck.y + Ckk.y), 0.5f*(Ckk.x - Ck.x));
      float s, c;
      sincosf(-3.14159265358979f * (float)k / (float)FFTN, &s, &c);
      float2 w = make_float2(c, s);
      float2 Fk  = caddf(E, cmulf(w, O));
      float2 Fkk = caddf(cconjf(E), cmulf(make_float2(-c, s), cconjf(O)));
      float2 Gk  = cmulf(Fk,  krow[k]);
      float2 Gkk = cmulf(Fkk, krow[kk]);
      float2 Xe  = make_float2(0.5f*(Gk.x + Gkk.x), 0.5f*(Gk.y - Gkk.y));
      float2 Dd  = make_float2(0.5f*(Gk.x - Gkk.x), 0.5f*(Gk.y + Gkk.y));
      float2 Xo  = cmulf(make_float2(c, -s), Dd);          // conj(w) * Dd
      other[k] = make_float2(Xe.x - Xo.y, Xe.y + Xo.x);
      float2 Xe2 = make_float2(0.5f*(Gkk.x + Gk.x), 0.5f*(Gkk.y - Gk.y));
      float2 Dd2 = make_float2(0.5f*(Gkk.x - Gk.x), 0.5f*(Gkk.y + Gk.y));
      float2 Xo2 = cmulf(make_float2(-c, -s), Dd2);        // -w * Dd2
      other[kk] = make_float2(Xe2.x - Xo2.y, Xe2.y + Xo2.x);
    }
  }
  float2* Z = fft2048(other, C2, tw, true, tid);
  const float sc = 1.0f / (float)FFTN;
  #pragma unroll
  for (int i = 0; i < 4; ++i) {
    int j = tid + i*NT;
    rrow[j] = make_float2(Z[j].x * sc, Z[j].y * sc);
  }
}

// (B,H,L) -> (B,L,H) transpose fused with + D*r and exact GELU
__global__ __launch_bounds__(256) void ktback(const float* __restrict__ yT, const float* __restrict__ r,
                                              const float* __restrict__ Dp, float* __restrict__ out)
{
  __shared__ float tile[32][33];
  int tx = threadIdx.x & 31, ty = threadIdx.x >> 5;
  int h0 = blockIdx.x * 32, l0 = blockIdx.y * 32, b = blockIdx.z;
  const float* s = yT + ((size_t)b*SSM_H + h0)*SSM_L + l0;
  #pragma unroll
  for (int i = 0; i < 4; ++i) { int row = ty + i*8; tile[row][tx] = s[(size_t)row*SSM_L + tx]; }
  __syncthreads();
  float Dv = Dp[0];
  float* o = out + ((size_t)b*SSM_L + l0)*SSM_H + h0;
  const float* rr = r + ((size_t)b*SSM_L + l0)*SSM_H + h0;
  #pragma unroll
  for (int i = 0; i < 4; ++i) {
    int row = ty + i*8;
    float x = tile[tx][row] + Dv * rr[(size_t)row*SSM_H + tx];
    float g = 0.5f * x * (1.0f + erff(x * 0.70710678118654752f));
    o[(size_t)row*SSM_H + tx] = g;
  }
}

extern "C" void kernel_launch(void* const* d_in, const int* in_sizes, int n_in,
                              void* d_out, int out_size, void* d_ws, size_t ws_size,
                              hipStream_t stream)
{
  const float* r       = (const float*)d_in[0];
  const float* B_re    = (const float*)d_in[1];
  const float* B_im    = (const float*)d_in[2];
  const float* C_re    = (const float*)d_in[3];
  const float* C_im    = (const float*)d_in[4];
  const float* P_re    = (const float*)d_in[5];
  const float* P_im    = (const float*)d_in[6];
  const float* Q_re    = (const float*)d_in[7];
  const float* Q_im    = (const float*)d_in[8];
  const float* diag_re = (const float*)d_in[9];
  const float* diag_im = (const float*)d_in[10];
  const float* step    = (const float*)d_in[11];
  const float* Dp      = (const float*)d_in[12];
  float* out = (float*)d_out;

  char* p = (char*)d_ws;
  float*  rT    = (float*)p;  p += (size_t)SSM_B*SSM_H*SSM_L*sizeof(float);   // 64 MiB
  float2* cdenT = (float2*)p; p += (size_t)SSM_N*SSM_L*sizeof(float2);        // 1 MiB
  float2* f2v   = (float2*)p; p += (size_t)SSM_L*sizeof(float2);
  float2* facv  = (float2*)p; p += (size_t)SSM_L*sizeof(float2);
  float2* Kf    = (float2*)p; p += (size_t)SSM_H*KFS*sizeof(float2);          // ~16.8 MiB

  kernel_cden<<<SSM_L/NT, NT, 0, stream>>>(B_re, B_im, P_re, P_im, Q_re, Q_im,
                                           diag_re, diag_im, step, cdenT, f2v, facv);
  kernel_khat<<<SSM_H, NT, 0, stream>>>(C_re, C_im, B_re, B_im, P_re, P_im,
                                        cdenT, f2v, facv, Kf);
  ktranspose<<<dim3(SSM_H/32, SSM_L/32, SSM_B), 256, 0, stream>>>(r, rT);
  kernel_conv<<<SSM_B*SSM_H, NT, 0, stream>>>(rT, Kf);
  ktback<<<dim3(SSM_H/32, SSM_L/32, SSM_B), 256, 0, stream>>>(rT, r, Dp, out);
}

// Round 2
// 355.893 us; speedup vs baseline: 1.2333x; 1.2333x over previous
//
#include <hip/hip_runtime.h>
#include <math.h>

#define SSM_N 64
#define SSM_H 1024
#define SSM_L 2048
#define SSM_B 8
#define FFTN 2048
#define NT 256
#define KFS 2052   // row stride (float2) for Kf, 2049 used

// XOR swizzle for LDS float2 indices: breaks stride-8/64 write conflicts (<=4-way),
// keeps lane-consecutive accesses conflict-free, zero extra LDS.
#define PSWZ(a) ((a) ^ (((a) >> 4) & 15))

__device__ __forceinline__ float2 cmulf(float2 a, float2 b){ return make_float2(a.x*b.x - a.y*b.y, a.x*b.y + a.y*b.x); }
__device__ __forceinline__ float2 caddf(float2 a, float2 b){ return make_float2(a.x+b.x, a.y+b.y); }
__device__ __forceinline__ float2 csubf(float2 a, float2 b){ return make_float2(a.x-b.x, a.y-b.y); }
__device__ __forceinline__ float2 cconjf(float2 a){ return make_float2(a.x, -a.y); }

// multiply by -i (forward) / +i (inverse)
template<bool INV> __device__ __forceinline__ float2 mul_mi(float2 a){
  return INV ? make_float2(-a.y, a.x) : make_float2(a.y, -a.x);
}
// multiply by w8 = (1-i)/sqrt2 (forward) / conj (inverse)
template<bool INV> __device__ __forceinline__ float2 mul_w81(float2 a){
  const float r = 0.70710678118654752440f;
  return INV ? make_float2((a.x - a.y)*r, (a.y + a.x)*r)
             : make_float2((a.x + a.y)*r, (a.y - a.x)*r);
}
// multiply by w8^3 = (-1-i)/sqrt2 (forward) / conj (inverse)
template<bool INV> __device__ __forceinline__ float2 mul_w83(float2 a){
  const float r = 0.70710678118654752440f;
  return INV ? make_float2(-(a.x + a.y)*r, (a.x - a.y)*r)
             : make_float2((a.y - a.x)*r, -(a.x + a.y)*r);
}

// One Stockham radix-8 stage, span S. 256 threads, one butterfly each.
// reads src[tid + q*256], writes dst[i + 8*(tid-i) + p*S], i = tid % S.
// twiddle w^p with w = exp(-2pi*i*(tid - i)/2048) (conj if INV).
template<bool INV, int S>
__device__ __forceinline__ void stage8(const float2* __restrict__ src, float2* __restrict__ dst,
                                       const float2* __restrict__ tw, int tid)
{
  float2 x[8];
  #pragma unroll
  for (int q = 0; q < 8; ++q) x[q] = src[PSWZ(tid + q*256)];
  float2 t0=caddf(x[0],x[4]), t4=csubf(x[0],x[4]);
  float2 t1=caddf(x[1],x[5]), t5=csubf(x[1],x[5]);
  float2 t2=caddf(x[2],x[6]), t6=csubf(x[2],x[6]);
  float2 t3=caddf(x[3],x[7]), t7=csubf(x[3],x[7]);
  // even outputs: DFT4 of t0..t3
  float2 b0=caddf(t0,t2), b2=csubf(t0,t2), b1=caddf(t1,t3), b3=csubf(t1,t3);
  float2 mb3 = mul_mi<INV>(b3);
  float2 y0=caddf(b0,b1), y4=csubf(b0,b1), y2=caddf(b2,mb3), y6=csubf(b2,mb3);
  // odd outputs: DFT4 of (t4, t5*w8, t6*(-i), t7*w8^3)
  float2 v1 = mul_w81<INV>(t5), v2 = mul_mi<INV>(t6), v3 = mul_w83<INV>(t7);
  float2 a0=caddf(t4,v2), a2=csubf(t4,v2), a1=caddf(v1,v3), a3=csubf(v1,v3);
  float2 ma3 = mul_mi<INV>(a3);
  float2 y1=caddf(a0,a1), y5=csubf(a0,a1), y3=caddf(a2,ma3), y7=csubf(a2,ma3);
  int i = tid & (S-1);
  int base = i + ((tid - i) << 3);
  float2 w1 = tw[PSWZ(tid - i)];   // (tid/S)*S < 1024 always
  if (INV) w1.y = -w1.y;
  float2 w2 = cmulf(w1,w1);
  float2 w3 = cmulf(w2,w1);
  float2 w4 = cmulf(w2,w2);
  float2 w5 = cmulf(w3,w2);
  float2 w6 = cmulf(w3,w3);
  float2 w7 = cmulf(w4,w3);
  dst[PSWZ(base)]     = y0;
  dst[PSWZ(base+S)]   = cmulf(y1,w1);
  dst[PSWZ(base+2*S)] = cmulf(y2,w2);
  dst[PSWZ(base+3*S)] = cmulf(y3,w3);
  dst[PSWZ(base+4*S)] = cmulf(y4,w4);
  dst[PSWZ(base+5*S)] = cmulf(y5,w5);
  dst[PSWZ(base+6*S)] = cmulf(y6,w6);
  dst[PSWZ(base+7*S)] = cmulf(y7,w7);
}

// Final radix-4 stage, span 512 (k=0 -> no twiddles). 2 butterflies/thread.
template<bool INV>
__device__ __forceinline__ void stage4_512(const float2* __restrict__ src, float2* __restrict__ dst, int tid)
{
  #pragma unroll
  for (int hh = 0; hh < 2; ++hh) {
    int idx = tid + hh*256;
    float2 x0=src[PSWZ(idx)], x1=src[PSWZ(idx+512)], x2=src[PSWZ(idx+1024)], x3=src[PSWZ(idx+1536)];
    float2 a0=caddf(x0,x2), a2=csubf(x0,x2), a1=caddf(x1,x3), a3=csubf(x1,x3);
    float2 m = mul_mi<INV>(a3);
    dst[PSWZ(idx)]      = caddf(a0,a1);
    dst[PSWZ(idx+512)]  = caddf(a2,m);
    dst[PSWZ(idx+1024)] = csubf(a0,a1);
    dst[PSWZ(idx+1536)] = csubf(a2,m);
  }
}

// 2048-pt complex FFT, input in A (PSWZ layout), result in A. B is scratch.
// tw[PSWZ(j)] = exp(-2pi*i*j/2048), j<1024. INV => conjugate transform (unscaled).
template<bool INV>
__device__ void fft2048_reg(float2* A, float2* B, const float2* tw, int tid)
{
  __syncthreads();
  stage8<INV,1>(A, B, tw, tid);
  __syncthreads();
  stage8<INV,8>(B, A, tw, tid);
  __syncthreads();
  stage8<INV,64>(A, B, tw, tid);
  __syncthreads();
  stage4_512<INV>(B, A, tid);
  __syncthreads();
}

__device__ __forceinline__ void init_tw(float2* tw, int tid)
{
  #pragma unroll
  for (int i = 0; i < 4; ++i) {
    int j = tid + i*NT;
    float s, c;
    sincosf(-6.2831853071795864769f * (float)j / (float)FFTN, &s, &c);
    tw[PSWZ(j)] = make_float2(c, s);
  }
}

// Stage 1a: cden (transposed to (N,L)), f2 = 2/(1+z), fac = k10/(1+k11). fp64 internally.
__global__ __launch_bounds__(256) void kernel_cden(
    const float* __restrict__ B_re, const float* __restrict__ B_im,
    const float* __restrict__ P_re, const float* __restrict__ P_im,
    const float* __restrict__ Q_re, const float* __restrict__ Q_im,
    const float* __restrict__ diag_re, const float* __restrict__ diag_im,
    const float* __restrict__ step,
    float2* __restrict__ cdenT, float2* __restrict__ f2v, float2* __restrict__ facv)
{
  int l = blockIdx.x * blockDim.x + threadIdx.x;
  if (l >= SSM_L) return;
  double stepc = (double)step[0]; if (stepc < 1e-6) stepc = 1e-6;
  double ang = -2.0 * 3.14159265358979323846 * (double)l / (double)SSM_L;
  double zr = cos(ang), zi = sin(ang);
  double dr = 1.0 + zr, di = zi;
  double nr = 1.0 - zr, ni = -zi;
  double den = dr*dr + di*di;
  double i2s = 2.0 / stepc;
  double gr = i2s * (nr*dr + ni*di) / den;
  double gi = i2s * (ni*dr - nr*di) / den;
  f2v[l] = make_float2((float)(2.0*dr/den), (float)(-2.0*di/den));
  double k10r=0.0, k10i=0.0, k11r=0.0, k11i=0.0;
  for (int n = 0; n < SSM_N; ++n) {
    double ar = gr - (double)diag_re[n];
    double ai = gi - (double)diag_im[n];
    double d2 = ar*ar + ai*ai;
    double cr = ar/d2, ci = -ai/d2;
    cdenT[n*SSM_L + l] = make_float2((float)cr, (float)ci);
    double qr = (double)Q_re[n], qi = (double)Q_im[n];
    double br = (double)B_re[n], bi = (double)B_im[n];
    double pr = (double)P_re[n], pi = (double)P_im[n];
    double qbr = qr*br - qi*bi, qbi = qr*bi + qi*br;
    double qpr = qr*pr - qi*pi, qpi = qr*pi + qi*pr;
    k10r += qbr*cr - qbi*ci; k10i += qbr*ci + qbi*cr;
    k11r += qpr*cr - qpi*ci; k11i += qpr*ci + qpi*cr;
  }
  double er = 1.0 + k11r, ei = k11i;
  double ed = er*er + ei*ei;
  facv[l] = make_float2((float)((k10r*er + k10i*ei)/ed), (float)((k10i*er - k10r*ei)/ed));
}

// Stage 1b: per channel h: at_roots -> ifft -> K -> rfft4096 (packed) -> Kf row.
__global__ __launch_bounds__(NT, 4) void kernel_khat(
    const float* __restrict__ C_re, const float* __restrict__ C_im,
    const float* __restrict__ B_re, const float* __restrict__ B_im,
    const float* __restrict__ P_re, const float* __restrict__ P_im,
    const float2* __restrict__ cdenT,
    const float2* __restrict__ f2v, const float2* __restrict__ facv,
    float2* __restrict__ Kf)
{
  __shared__ float2 bufA[FFTN];
  __shared__ float2 bufB[FFTN];
  __shared__ float2 tw[FFTN/2];
  int tid = threadIdx.x;
  int h = blockIdx.x;
  // CB/CP alias bufB's first 128 entries: dead once the first FFT stage writes bufB.
  float2* CBs = bufB;
  float2* CPs = bufB + SSM_N;
  init_tw(tw, tid);
  if (tid < SSM_N) {
    float2 cc = make_float2(C_re[h*SSM_N + tid], C_im[h*SSM_N + tid]);
    CBs[tid] = cmulf(cc, make_float2(B_re[tid], B_im[tid]));
    CPs[tid] = cmulf(cc, make_float2(P_re[tid], P_im[tid]));
  }
  __syncthreads();
  float2 k00[8], k01[8];
  #pragma unroll
  for (int i = 0; i < 8; ++i) { k00[i] = make_float2(0.f,0.f); k01[i] = make_float2(0.f,0.f); }
  for (int n = 0; n < SSM_N; ++n) {
    float2 cb = CBs[n], cp = CPs[n];
    #pragma unroll
    for (int i = 0; i < 8; ++i) {
      float2 cd = cdenT[n*SSM_L + tid + i*NT];
      k00[i] = caddf(k00[i], cmulf(cb, cd));
      k01[i] = caddf(k01[i], cmulf(cp, cd));
    }
  }
  #pragma unroll
  for (int i = 0; i < 8; ++i) {
    int l = tid + i*NT;
    bufA[PSWZ(l)] = cmulf(f2v[l], csubf(k00[i], cmulf(k01[i], facv[l])));
  }
  // K = Re(ifft(at_roots))/N ; fft entry-sync covers bufA fill + CB death
  fft2048_reg<true>(bufA, bufB, tw, tid);       // result in bufA
  const float scale = 1.0f / (float)FFTN;
  #pragma unroll
  for (int i = 0; i < 8; ++i) {                 // pack even/odd of zero-padded K into bufB
    int j = tid + i*NT;
    float2 v = make_float2(0.f, 0.f);
    if (j < FFTN/2) v = make_float2(bufA[PSWZ(2*j)].x * scale, bufA[PSWZ(2*j+1)].x * scale);
    bufB[PSWZ(j)] = v;
  }
  fft2048_reg<false>(bufB, bufA, tw, tid);      // result in bufB = C2
  float2* krow = Kf + (size_t)h * KFS;
  #pragma unroll
  for (int i = 0; i < 4; ++i) {
    int k = tid + i*NT;
    if (k == 0) {
      float2 c0 = bufB[PSWZ(0)];
      krow[0]       = make_float2(c0.x + c0.y, 0.f);
      krow[FFTN]    = make_float2(c0.x - c0.y, 0.f);
      krow[FFTN/2]  = cconjf(bufB[PSWZ(FFTN/2)]);
    } else {
      int kk = FFTN - k;
      float2 Ck = bufB[PSWZ(k)], Ckk = bufB[PSWZ(kk)];
      float2 E = make_float2(0.5f*(Ck.x + Ckk.x), 0.5f*(Ck.y - Ckk.y));
      float2 O = make_float2(0.5f*(Ck.y + Ckk.y), 0.5f*(Ckk.x - Ck.x));
      float s, c;
      sincosf(-3.14159265358979f * (float)k / (float)FFTN, &s, &c);
      float2 w = make_float2(c, s);
      krow[k]  = caddf(E, cmulf(w, O));
      krow[kk] = caddf(cconjf(E), cmulf(make_float2(-c, s), cconjf(O)));
    }
  }
}

// (B,L,H) -> (B,H,L) tiled transpose
__global__ __launch_bounds__(256) void ktranspose(const float* __restrict__ src, float* __restrict__ dst)
{
  __shared__ float tile[32][33];
  int tx = threadIdx.x & 31, ty = threadIdx.x >> 5;
  int h0 = blockIdx.x * 32, l0 = blockIdx.y * 32, b = blockIdx.z;
  const float* s = src + ((size_t)b*SSM_L + l0)*SSM_H + h0;
  #pragma unroll
  for (int i = 0; i < 4; ++i) { int row = ty + i*8; tile[row][tx] = s[(size_t)row*SSM_H + tx]; }
  __syncthreads();
  float* d = dst + ((size_t)b*SSM_H + h0)*SSM_L + l0;
  #pragma unroll
  for (int i = 0; i < 4; ++i) { int row = ty + i*8; d[(size_t)row*SSM_L + tx] = tile[tx][row]; }
}

// Stage 2: per (b,h) row, in place on rT: rfft4096 (packed) -> *Kf -> irfft4096, keep first L.
__global__ __launch_bounds__(NT, 4) void kernel_conv(float* __restrict__ rT, const float2* __restrict__ Kf)
{
  __shared__ float2 bufA[FFTN];
  __shared__ float2 bufB[FFTN];
  __shared__ float2 tw[FFTN/2];
  int tid = threadIdx.x;
  int row = blockIdx.x;
  int h = row & (SSM_H - 1);
  init_tw(tw, tid);
  float2* rrow = (float2*)(rT + (size_t)row * SSM_L);
  #pragma unroll
  for (int i = 0; i < 8; ++i) {
    int j = tid + i*NT;
    bufA[PSWZ(j)] = (j < SSM_L/2) ? rrow[j] : make_float2(0.f, 0.f);
  }
  fft2048_reg<false>(bufA, bufB, tw, tid);      // C2 in bufA
  const float2* krow = Kf + (size_t)h * KFS;
  #pragma unroll
  for (int i = 0; i < 4; ++i) {                 // unpack -> multiply Kf -> repack, into bufB
    int k = tid + i*NT;
    if (k == 0) {
      float2 c0 = bufA[PSWZ(0)];
      float F0 = c0.x + c0.y, Fn = c0.x - c0.y;
      float2 K0 = krow[0], Kn = krow[FFTN];
      float2 G0 = make_float2(F0*K0.x, F0*K0.y);
      float2 Gn = make_float2(Fn*Kn.x, Fn*Kn.y);
      float2 Xe = make_float2(0.5f*(G0.x+Gn.x), 0.5f*(G0.y+Gn.y));
      float2 Xo = make_float2(0.5f*(G0.x-Gn.x), 0.5f*(G0.y-Gn.y));
      bufB[PSWZ(0)] = make_float2(Xe.x - Xo.y, Xe.y + Xo.x);
      float2 Gm = cmulf(cconjf(bufA[PSWZ(FFTN/2)]), krow[FFTN/2]);
      bufB[PSWZ(FFTN/2)] = cconjf(Gm);
    } else {
      int kk = FFTN - k;
      float2 Ck = bufA[PSWZ(k)], Ckk = bufA[PSWZ(kk)];
      float2 E = make_float2(0.5f*(Ck.x + Ckk.x), 0.5f*(Ck.y - Ckk.y));
      float2 O = make_float2(0.5f*(Ck.y + Ckk.y), 0.5f*(Ckk.x - Ck.x));
      float s, c;
      sincosf(-3.14159265358979f * (float)k / (float)FFTN, &s, &c);
      float2 w = make_float2(c, s);
      float2 Fk  = caddf(E, cmulf(w, O));
      float2 Fkk = caddf(cconjf(E), cmulf(make_float2(-c, s), cconjf(O)));
      float2 Gk  = cmulf(Fk,  krow[k]);
      float2 Gkk = cmulf(Fkk, krow[kk]);
      float2 Xe  = make_float2(0.5f*(Gk.x + Gkk.x), 0.5f*(Gk.y - Gkk.y));
      float2 Dd  = make_float2(0.5f*(Gk.x - Gkk.x), 0.5f*(Gk.y + Gkk.y));
      float2 Xo  = cmulf(make_float2(c, -s), Dd);          // conj(w) * Dd
      bufB[PSWZ(k)] = make_float2(Xe.x - Xo.y, Xe.y + Xo.x);
      float2 Xe2 = make_float2(0.5f*(Gkk.x + Gk.x), 0.5f*(Gkk.y - Gk.y));
      float2 Dd2 = make_float2(0.5f*(Gkk.x - Gk.x), 0.5f*(Gkk.y + Gk.y));
      float2 Xo2 = cmulf(make_float2(-c, -s), Dd2);        // -w * Dd2
      bufB[PSWZ(kk)] = make_float2(Xe2.x - Xo2.y, Xe2.y + Xo2.x);
    }
  }
  fft2048_reg<true>(bufB, bufA, tw, tid);       // result in bufB
  const float sc = 1.0f / (float)FFTN;
  #pragma unroll
  for (int i = 0; i < 4; ++i) {
    int j = tid + i*NT;
    float2 z = bufB[PSWZ(j)];
    rrow[j] = make_float2(z.x * sc, z.y * sc);
  }
}

// (B,H,L) -> (B,L,H) transpose fused with + D*r and exact GELU
__global__ __launch_bounds__(256) void ktback(const float* __restrict__ yT, const float* __restrict__ r,
                                              const float* __restrict__ Dp, float* __restrict__ out)
{
  __shared__ float tile[32][33];
  int tx = threadIdx.x & 31, ty = threadIdx.x >> 5;
  int h0 = blockIdx.x * 32, l0 = blockIdx.y * 32, b = blockIdx.z;
  const float* s = yT + ((size_t)b*SSM_H + h0)*SSM_L + l0;
  #pragma unroll
  for (int i = 0; i < 4; ++i) { int row = ty + i*8; tile[row][tx] = s[(size_t)row*SSM_L + tx]; }
  __syncthreads();
  float Dv = Dp[0];
  float* o = out + ((size_t)b*SSM_L + l0)*SSM_H + h0;
  const float* rr = r + ((size_t)b*SSM_L + l0)*SSM_H + h0;
  #pragma unroll
  for (int i = 0; i < 4; ++i) {
    int row = ty + i*8;
    float x = tile[tx][row] + Dv * rr[(size_t)row*SSM_H + tx];
    float g = 0.5f * x * (1.0f + erff(x * 0.70710678118654752f));
    o[(size_t)row*SSM_H + tx] = g;
  }
}

extern "C" void kernel_launch(void* const* d_in, const int* in_sizes, int n_in,
                              void* d_out, int out_size, void* d_ws, size_t ws_size,
                              hipStream_t stream)
{
  const float* r       = (const float*)d_in[0];
  const float* B_re    = (const float*)d_in[1];
  const float* B_im    = (const float*)d_in[2];
  const float* C_re    = (const float*)d_in[3];
  const float* C_im    = (const float*)d_in[4];
  const float* P_re    = (const float*)d_in[5];
  const float* P_im    = (const float*)d_in[6];
  const float* Q_re    = (const float*)d_in[7];
  const float* Q_im    = (const float*)d_in[8];
  const float* diag_re = (const float*)d_in[9];
  const float* diag_im = (const float*)d_in[10];
  const float* step    = (const float*)d_in[11];
  const float* Dp      = (const float*)d_in[12];
  float* out = (float*)d_out;

  char* p = (char*)d_ws;
  float*  rT    = (float*)p;  p += (size_t)SSM_B*SSM_H*SSM_L*sizeof(float);   // 64 MiB
  float2* cdenT = (float2*)p; p += (size_t)SSM_N*SSM_L*sizeof(float2);        // 1 MiB
  float2* f2v   = (float2*)p; p += (size_t)SSM_L*sizeof(float2);
  float2* facv  = (float2*)p; p += (size_t)SSM_L*sizeof(float2);
  float2* Kf    = (float2*)p; p += (size_t)SSM_H*KFS*sizeof(float2);          // ~16.8 MiB

  kernel_cden<<<SSM_L/NT, NT, 0, stream>>>(B_re, B_im, P_re, P_im, Q_re, Q_im,
                                           diag_re, diag_im, step, cdenT, f2v, facv);
  kernel_khat<<<SSM_H, NT, 0, stream>>>(C_re, C_im, B_re, B_im, P_re, P_im,
                                        cdenT, f2v, facv, Kf);
  ktranspose<<<dim3(SSM_H/32, SSM_L/32, SSM_B), 256, 0, stream>>>(r, rT);
  kernel_conv<<<SSM_B*SSM_H, NT, 0, stream>>>(rT, Kf);
  ktback<<<dim3(SSM_H/32, SSM_L/32, SSM_B), 256, 0, stream>>>(rT, r, Dp, out);
}

// Round 3
// 344.472 us; speedup vs baseline: 1.2742x; 1.0332x over previous
//
#include <hip/hip_runtime.h>
#include <math.h>

#define SSM_N 64
#define SSM_H 1024
#define SSM_L 2048
#define SSM_B 8
#define FFTN 2048
#define NT 256
#define KFS 2052   // row stride (float2) for Kf, 2049 used

// pad-every-16 LDS layout: float2 logical index a -> physical a + (a>>4).
// Key algebraic facts (all verified, no carries):
//   PADI(t + 256q)   = PADI(t) + 272q          (reads, all stages)
//   PADI(8t + p)     = 8t + (t>>1) + p, p<8    (S=1 writes: consecutive!)
//   PADI(b + 64p)    = PADI(b) + 68p           (S=64 writes)
//   PADI(i + 512p)   = PADI(i) + 544p          (radix-4 stage)
//   PADI(2m)+1       = PADI(2m+1)              (pairs stay adjacent -> b128)
#define PADI(a) ((a) + ((a) >> 4))
#define PBUF 2176   // 2048 + 128 pad

__device__ __forceinline__ float2 cmulf(float2 a, float2 b){ return make_float2(a.x*b.x - a.y*b.y, a.x*b.y + a.y*b.x); }
__device__ __forceinline__ float2 caddf(float2 a, float2 b){ return make_float2(a.x+b.x, a.y+b.y); }
__device__ __forceinline__ float2 csubf(float2 a, float2 b){ return make_float2(a.x-b.x, a.y-b.y); }
__device__ __forceinline__ float2 cconjf(float2 a){ return make_float2(a.x, -a.y); }

template<bool INV> __device__ __forceinline__ float2 mul_mi(float2 a){
  return INV ? make_float2(-a.y, a.x) : make_float2(a.y, -a.x);
}
template<bool INV> __device__ __forceinline__ float2 mul_w81(float2 a){
  const float r = 0.70710678118654752440f;
  return INV ? make_float2((a.x - a.y)*r, (a.y + a.x)*r)
             : make_float2((a.x + a.y)*r, (a.y - a.x)*r);
}
template<bool INV> __device__ __forceinline__ float2 mul_w83(float2 a){
  const float r = 0.70710678118654752440f;
  return INV ? make_float2(-(a.x + a.y)*r, (a.x - a.y)*r)
             : make_float2((a.y - a.x)*r, -(a.x + a.y)*r);
}

// One Stockham radix-8 stage, span S, padded layout.
template<bool INV, int S>
__device__ __forceinline__ void stage8p(const float2* __restrict__ src, float2* __restrict__ dst,
                                        const float2* __restrict__ tw, int t)
{
  float2 x[8];
  const float2* sp = src + PADI(t);
  #pragma unroll
  for (int q = 0; q < 8; ++q) x[q] = sp[272*q];
  float2 t0=caddf(x[0],x[4]), t4=csubf(x[0],x[4]);
  float2 t1=caddf(x[1],x[5]), t5=csubf(x[1],x[5]);
  float2 t2=caddf(x[2],x[6]), t6=csubf(x[2],x[6]);
  float2 t3=caddf(x[3],x[7]), t7=csubf(x[3],x[7]);
  float2 b0=caddf(t0,t2), b2=csubf(t0,t2), b1=caddf(t1,t3), b3=csubf(t1,t3);
  float2 mb3 = mul_mi<INV>(b3);
  float2 y0=caddf(b0,b1), y4=csubf(b0,b1), y2=caddf(b2,mb3), y6=csubf(b2,mb3);
  float2 v1 = mul_w81<INV>(t5), v2 = mul_mi<INV>(t6), v3 = mul_w83<INV>(t7);
  float2 a0=caddf(t4,v2), a2=csubf(t4,v2), a1=caddf(v1,v3), a3=csubf(v1,v3);
  float2 ma3 = mul_mi<INV>(a3);
  float2 y1=caddf(a0,a1), y5=csubf(a0,a1), y3=caddf(a2,ma3), y7=csubf(a2,ma3);
  int i = t & (S-1);
  int j = t - i;                 // twiddle exponent, <= 248 -> 256-entry table
  float2 w1 = tw[j];
  if (INV) w1.y = -w1.y;
  float2 w2 = cmulf(w1,w1);
  float2 w3 = cmulf(w2,w1);
  float2 w4 = cmulf(w2,w2);
  float2 w5 = cmulf(w3,w2);
  float2 w6 = cmulf(w3,w3);
  float2 w7 = cmulf(w4,w3);
  int base = i + (j << 3);       // i + 8*(t-i)
  if (S == 1) {
    float2* wp = dst + ((t << 3) + (t >> 1));   // PADI(8t), offsets +p constant
    wp[0] = y0;          wp[1] = cmulf(y1,w1);
    wp[2] = cmulf(y2,w2); wp[3] = cmulf(y3,w3);
    wp[4] = cmulf(y4,w4); wp[5] = cmulf(y5,w5);
    wp[6] = cmulf(y6,w6); wp[7] = cmulf(y7,w7);
  } else if (S == 64) {
    float2* wp = dst + PADI(base);              // offsets +68p constant
    wp[0]     = y0;          wp[68]   = cmulf(y1,w1);
    wp[2*68]  = cmulf(y2,w2); wp[3*68] = cmulf(y3,w3);
    wp[4*68]  = cmulf(y4,w4); wp[5*68] = cmulf(y5,w5);
    wp[6*68]  = cmulf(y6,w6); wp[7*68] = cmulf(y7,w7);
  } else {
    dst[PADI(base)]       = y0;
    dst[PADI(base+S)]     = cmulf(y1,w1);
    dst[PADI(base+2*S)]   = cmulf(y2,w2);
    dst[PADI(base+3*S)]   = cmulf(y3,w3);
    dst[PADI(base+4*S)]   = cmulf(y4,w4);
    dst[PADI(base+5*S)]   = cmulf(y5,w5);
    dst[PADI(base+6*S)]   = cmulf(y6,w6);
    dst[PADI(base+7*S)]   = cmulf(y7,w7);
  }
}

// Final radix-4 stage, span 512 (k=0 -> no twiddles).
template<bool INV>
__device__ __forceinline__ void stage4p(const float2* __restrict__ src, float2* __restrict__ dst, int t)
{
  #pragma unroll
  for (int hh = 0; hh < 2; ++hh) {
    int pidx = PADI(t + 256*hh);
    const float2* sp = src + pidx;
    float2 x0=sp[0], x1=sp[544], x2=sp[1088], x3=sp[1632];
    float2 a0=caddf(x0,x2), a2=csubf(x0,x2), a1=caddf(x1,x3), a3=csubf(x1,x3);
    float2 m = mul_mi<INV>(a3);
    float2* wp = dst + pidx;
    wp[0]    = caddf(a0,a1);
    wp[544]  = caddf(a2,m);
    wp[1088] = csubf(a0,a1);
    wp[1632] = csubf(a2,m);
  }
}

// 2048-pt complex FFT in padded layout, input in A, result in A. B scratch.
template<bool INV>
__device__ void fft2048_pad(float2* A, float2* B, const float2* tw, int t)
{
  __syncthreads();
  stage8p<INV,1>(A, B, tw, t);
  __syncthreads();
  stage8p<INV,8>(B, A, tw, t);
  __syncthreads();
  stage8p<INV,64>(A, B, tw, t);
  __syncthreads();
  stage4p<INV>(B, A, t);
  __syncthreads();
}

__device__ __forceinline__ void init_tw(float2* tw, int t)
{
  // only exponents 0..248 are used by the stages
  float s, c;
  sincosf(-6.2831853071795864769f * (float)t / (float)FFTN, &s, &c);
  tw[t] = make_float2(c, s);
}

// Stage 1a: cden (transposed (N,L)), f2 = 2/(1+z), fac = k10/(1+k11). fp64 internally.
__global__ __launch_bounds__(256) void kernel_cden(
    const float* __restrict__ B_re, const float* __restrict__ B_im,
    const float* __restrict__ P_re, const float* __restrict__ P_im,
    const float* __restrict__ Q_re, const float* __restrict__ Q_im,
    const float* __restrict__ diag_re, const float* __restrict__ diag_im,
    const float* __restrict__ step,
    float2* __restrict__ cdenT, float2* __restrict__ f2v, float2* __restrict__ facv)
{
  int l = blockIdx.x * blockDim.x + threadIdx.x;
  if (l >= SSM_L) return;
  double stepc = (double)step[0]; if (stepc < 1e-6) stepc = 1e-6;
  double ang = -2.0 * 3.14159265358979323846 * (double)l / (double)SSM_L;
  double zr = cos(ang), zi = sin(ang);
  double dr = 1.0 + zr, di = zi;
  double nr = 1.0 - zr, ni = -zi;
  double den = dr*dr + di*di;
  double i2s = 2.0 / stepc;
  double gr = i2s * (nr*dr + ni*di) / den;
  double gi = i2s * (ni*dr - nr*di) / den;
  f2v[l] = make_float2((float)(2.0*dr/den), (float)(-2.0*di/den));
  double k10r=0.0, k10i=0.0, k11r=0.0, k11i=0.0;
  for (int n = 0; n < SSM_N; ++n) {
    double ar = gr - (double)diag_re[n];
    double ai = gi - (double)diag_im[n];
    double d2 = ar*ar + ai*ai;
    double cr = ar/d2, ci = -ai/d2;
    cdenT[n*SSM_L + l] = make_float2((float)cr, (float)ci);
    double qr = (double)Q_re[n], qi = (double)Q_im[n];
    double br = (double)B_re[n], bi = (double)B_im[n];
    double pr = (double)P_re[n], pi = (double)P_im[n];
    double qbr = qr*br - qi*bi, qbi = qr*bi + qi*br;
    double qpr = qr*pr - qi*pi, qpi = qr*pi + qi*pr;
    k10r += qbr*cr - qbi*ci; k10i += qbr*ci + qbi*cr;
    k11r += qpr*cr - qpi*ci; k11i += qpr*ci + qpi*cr;
  }
  double er = 1.0 + k11r, ei = k11i;
  double ed = er*er + ei*ei;
  facv[l] = make_float2((float)((k10r*er + k10i*ei)/ed), (float)((k10i*er - k10r*ei)/ed));
}

// Stage 1b: 2 channels per block: contraction (k00,k01) -> per h: at_roots -> ifft
// -> K -> rfft4096 (packed) -> Kf row.
__global__ __launch_bounds__(NT, 2) void kernel_khat(
    const float* __restrict__ C_re, const float* __restrict__ C_im,
    const float* __restrict__ B_re, const float* __restrict__ B_im,
    const float* __restrict__ P_re, const float* __restrict__ P_im,
    const float2* __restrict__ cdenT,
    const float2* __restrict__ f2v, const float2* __restrict__ facv,
    float2* __restrict__ Kf)
{
  __shared__ float2 bufA[PBUF];
  __shared__ float2 bufB[PBUF];
  __shared__ float2 tw[256];
  int t = threadIdx.x;
  int h0 = blockIdx.x * 2;
  init_tw(tw, t);
  // stage CB/CP for both h into bufA[0..255] (dead once first FFT stage writes)
  if (t < 128) {
    int h = h0 + (t >> 6), n = t & 63;
    float2 cc = make_float2(C_re[h*SSM_N + n], C_im[h*SSM_N + n]);
    bufA[t]       = cmulf(cc, make_float2(B_re[n], B_im[n]));
    bufA[128 + t] = cmulf(cc, make_float2(P_re[n], P_im[n]));
  }
  __syncthreads();
  float2 k00[2][8], k01[2][8];
  #pragma unroll
  for (int h = 0; h < 2; ++h)
    #pragma unroll
    for (int i = 0; i < 8; ++i) { k00[h][i] = make_float2(0.f,0.f); k01[h][i] = make_float2(0.f,0.f); }
  for (int n = 0; n < SSM_N; ++n) {
    float2 cd[8];
    #pragma unroll
    for (int i = 0; i < 8; ++i) cd[i] = cdenT[n*SSM_L + t + i*NT];
    #pragma unroll
    for (int h = 0; h < 2; ++h) {
      float2 cb = bufA[h*64 + n], cp = bufA[128 + h*64 + n];
      #pragma unroll
      for (int i = 0; i < 8; ++i) {
        k00[h][i] = caddf(k00[h][i], cmulf(cb, cd[i]));
        k01[h][i] = caddf(k01[h][i], cmulf(cp, cd[i]));
      }
    }
  }
  for (int h = 0; h < 2; ++h) {
    __syncthreads();   // bufA free (prev readers done)
    #pragma unroll
    for (int i = 0; i < 8; ++i) {
      int l = t + i*NT;
      float2 f2 = f2v[l], fc = facv[l];
      bufA[PADI(l)] = cmulf(f2, csubf(k00[h][i], cmulf(k01[h][i], fc)));
    }
    fft2048_pad<true>(bufA, bufB, tw, t);       // result in bufA
    const float scale = 1.0f / (float)FFTN;
    #pragma unroll
    for (int i = 0; i < 8; ++i) {               // pack even/odd of zero-padded K
      int j = t + i*NT;
      float2 v = make_float2(0.f, 0.f);
      if (j < FFTN/2) {
        int pi2 = PADI(2*j);
        v = make_float2(bufA[pi2].x * scale, bufA[pi2+1].x * scale);
      }
      bufB[PADI(j)] = v;
    }
    fft2048_pad<false>(bufB, bufA, tw, t);      // result in bufB
    float2* krow = Kf + (size_t)(h0 + h) * KFS;
    #pragma unroll
    for (int i = 0; i < 4; ++i) {
      int k = t + i*NT;
      if (k == 0) {
        float2 c0 = bufB[0];
        krow[0]       = make_float2(c0.x + c0.y, 0.f);
        krow[FFTN]    = make_float2(c0.x - c0.y, 0.f);
        krow[FFTN/2]  = cconjf(bufB[PADI(FFTN/2)]);
      } else {
        int kk = FFTN - k;
        float2 Ck = bufB[PADI(k)], Ckk = bufB[PADI(kk)];
        float2 E = make_float2(0.5f*(Ck.x + Ckk.x), 0.5f*(Ck.y - Ckk.y));
        float2 O = make_float2(0.5f*(Ck.y + Ckk.y), 0.5f*(Ckk.x - Ck.x));
        float s, c;
        sincosf(-3.14159265358979f * (float)k / (float)FFTN, &s, &c);
        float2 w = make_float2(c, s);
        krow[k]  = caddf(E, cmulf(w, O));
        krow[kk] = caddf(cconjf(E), cmulf(make_float2(-c, s), cconjf(O)));
      }
    }
    __syncthreads();   // krow reads of bufB done before next-h bufA refill races FFT
  }
}

// (B,L,H) -> (B,H,L) tiled transpose
__global__ __launch_bounds__(256) void ktranspose(const float* __restrict__ src, float* __restrict__ dst)
{
  __shared__ float tile[32][33];
  int tx = threadIdx.x & 31, ty = threadIdx.x >> 5;
  int h0 = blockIdx.x * 32, l0 = blockIdx.y * 32, b = blockIdx.z;
  const float* s = src + ((size_t)b*SSM_L + l0)*SSM_H + h0;
  #pragma unroll
  for (int i = 0; i < 4; ++i) { int row = ty + i*8; tile[row][tx] = s[(size_t)row*SSM_H + tx]; }
  __syncthreads();
  float* d = dst + ((size_t)b*SSM_H + h0)*SSM_L + l0;
  #pragma unroll
  for (int i = 0; i < 4; ++i) { int row = ty + i*8; d[(size_t)row*SSM_L + tx] = tile[tx][row]; }
}

// Stage 2: per (b,h) row in rT: rfft4096 (packed) -> *Kf -> irfft4096, keep first L.
__global__ __launch_bounds__(NT, 4) void kernel_conv(float* __restrict__ rT, const float2* __restrict__ Kf)
{
  __shared__ float2 bufA[PBUF];
  __shared__ float2 bufB[PBUF];
  __shared__ float2 tw[256];
  int t = threadIdx.x;
  int row = blockIdx.x;
  int h = row & (SSM_H - 1);
  init_tw(tw, t);
  float* rrow = rT + (size_t)row * SSM_L;
  const float4* r4 = (const float4*)rrow;
  #pragma unroll
  for (int i = 0; i < 2; ++i) {                  // load 2048 reals as 1024 packed float2
    int j2 = t + i*NT;                           // float4 index < 512
    float4 v = r4[j2];
    int p = PADI(2*j2);
    bufA[p]   = make_float2(v.x, v.y);
    bufA[p+1] = make_float2(v.z, v.w);
  }
  #pragma unroll
  for (int i = 0; i < 2; ++i) {                  // zero pad upper half
    int base = 1024 + 2*(t + i*NT);
    int p = PADI(base);
    bufA[p]   = make_float2(0.f, 0.f);
    bufA[p+1] = make_float2(0.f, 0.f);
  }
  fft2048_pad<false>(bufA, bufB, tw, t);         // C2 in bufA
  const float2* krow = Kf + (size_t)h * KFS;
  #pragma unroll
  for (int i = 0; i < 4; ++i) {                  // unpack -> *Kf -> repack into bufB
    int k = t + i*NT;
    if (k == 0) {
      float2 c0 = bufA[0];
      float F0 = c0.x + c0.y, Fn = c0.x - c0.y;
      float2 K0 = krow[0], Kn = krow[FFTN];
      float2 G0 = make_float2(F0*K0.x, F0*K0.y);
      float2 Gn = make_float2(Fn*Kn.x, Fn*Kn.y);
      float2 Xe = make_float2(0.5f*(G0.x+Gn.x), 0.5f*(G0.y+Gn.y));
      float2 Xo = make_float2(0.5f*(G0.x-Gn.x), 0.5f*(G0.y-Gn.y));
      bufB[0] = make_float2(Xe.x - Xo.y, Xe.y + Xo.x);
      float2 Gm = cmulf(cconjf(bufA[PADI(FFTN/2)]), krow[FFTN/2]);
      bufB[PADI(FFTN/2)] = cconjf(Gm);
    } else {
      int kk = FFTN - k;
      float2 Ck = bufA[PADI(k)], Ckk = bufA[PADI(kk)];
      float2 E = make_float2(0.5f*(Ck.x + Ckk.x), 0.5f*(Ck.y - Ckk.y));
      float2 O = make_float2(0.5f*(Ck.y + Ckk.y), 0.5f*(Ckk.x - Ck.x));
      float s, c;
      sincosf(-3.14159265358979f * (float)k / (float)FFTN, &s, &c);
      float2 w = make_float2(c, s);
      float2 Fk  = caddf(E, cmulf(w, O));
      float2 Fkk = caddf(cconjf(E), cmulf(make_float2(-c, s), cconjf(O)));
      float2 Gk  = cmulf(Fk,  krow[k]);
      float2 Gkk = cmulf(Fkk, krow[kk]);
      float2 Xe  = make_float2(0.5f*(Gk.x + Gkk.x), 0.5f*(Gk.y - Gkk.y));
      float2 Dd  = make_float2(0.5f*(Gk.x - Gkk.x), 0.5f*(Gk.y + Gkk.y));
      float2 Xo  = cmulf(make_float2(c, -s), Dd);          // conj(w) * Dd
      bufB[PADI(k)] = make_float2(Xe.x - Xo.y, Xe.y + Xo.x);
      float2 Xe2 = make_float2(0.5f*(Gkk.x + Gk.x), 0.5f*(Gkk.y - Gk.y));
      float2 Dd2 = make_float2(0.5f*(Gkk.x - Gk.x), 0.5f*(Gkk.y + Gk.y));
      float2 Xo2 = cmulf(make_float2(-c, -s), Dd2);        // -w * Dd2
      bufB[PADI(kk)] = make_float2(Xe2.x - Xo2.y, Xe2.y + Xo2.x);
    }
  }
  fft2048_pad<true>(bufB, bufA, tw, t);          // result in bufB
  const float sc = 1.0f / (float)FFTN;
  float4* w4 = (float4*)rrow;
  #pragma unroll
  for (int i = 0; i < 2; ++i) {
    int j2 = t + i*NT;
    int p = PADI(2*j2);
    float2 z0 = bufB[p], z1 = bufB[p+1];
    w4[j2] = make_float4(z0.x*sc, z0.y*sc, z1.x*sc, z1.y*sc);
  }
}

// (B,H,L) -> (B,L,H) transpose fused with + D*r and exact GELU
__global__ __launch_bounds__(256) void ktback(const float* __restrict__ yT, const float* __restrict__ r,
                                              const float* __restrict__ Dp, float* __restrict__ out)
{
  __shared__ float tile[32][33];
  int tx = threadIdx.x & 31, ty = threadIdx.x >> 5;
  int h0 = blockIdx.x * 32, l0 = blockIdx.y * 32, b = blockIdx.z;
  const float* s = yT + ((size_t)b*SSM_H + h0)*SSM_L + l0;
  #pragma unroll
  for (int i = 0; i < 4; ++i) { int row = ty + i*8; tile[row][tx] = s[(size_t)row*SSM_L + tx]; }
  __syncthreads();
  float Dv = Dp[0];
  float* o = out + ((size_t)b*SSM_L + l0)*SSM_H + h0;
  const float* rr = r + ((size_t)b*SSM_L + l0)*SSM_H + h0;
  #pragma unroll
  for (int i = 0; i < 4; ++i) {
    int row = ty + i*8;
    float x = tile[tx][row] + Dv * rr[(size_t)row*SSM_H + tx];
    float g = 0.5f * x * (1.0f + erff(x * 0.70710678118654752f));
    o[(size_t)row*SSM_H + tx] = g;
  }
}

extern "C" void kernel_launch(void* const* d_in, const int* in_sizes, int n_in,
                              void* d_out, int out_size, void* d_ws, size_t ws_size,
                              hipStream_t stream)
{
  const float* r       = (const float*)d_in[0];
  const float* B_re    = (const float*)d_in[1];
  const float* B_im    = (const float*)d_in[2];
  const float* C_re    = (const float*)d_in[3];
  const float* C_im    = (const float*)d_in[4];
  const float* P_re    = (const float*)d_in[5];
  const float* P_im    = (const float*)d_in[6];
  const float* Q_re    = (const float*)d_in[7];
  const float* Q_im    = (const float*)d_in[8];
  const float* diag_re = (const float*)d_in[9];
  const float* diag_im = (const float*)d_in[10];
  const float* step    = (const float*)d_in[11];
  const float* Dp      = (const float*)d_in[12];
  float* out = (float*)d_out;

  char* p = (char*)d_ws;
  float*  rT    = (float*)p;  p += (size_t)SSM_B*SSM_H*SSM_L*sizeof(float);   // 64 MiB
  float2* cdenT = (float2*)p; p += (size_t)SSM_N*SSM_L*sizeof(float2);        // 1 MiB
  float2* f2v   = (float2*)p; p += (size_t)SSM_L*sizeof(float2);
  float2* facv  = (float2*)p; p += (size_t)SSM_L*sizeof(float2);
  float2* Kf    = (float2*)p; p += (size_t)SSM_H*KFS*sizeof(float2);          // ~16.8 MiB

  kernel_cden<<<SSM_L/NT, NT, 0, stream>>>(B_re, B_im, P_re, P_im, Q_re, Q_im,
                                           diag_re, diag_im, step, cdenT, f2v, facv);
  kernel_khat<<<SSM_H/2, NT, 0, stream>>>(C_re, C_im, B_re, B_im, P_re, P_im,
                                          cdenT, f2v, facv, Kf);
  ktranspose<<<dim3(SSM_H/32, SSM_L/32, SSM_B), 256, 0, stream>>>(r, rT);
  kernel_conv<<<SSM_B*SSM_H, NT, 0, stream>>>(rT, Kf);
  ktback<<<dim3(SSM_H/32, SSM_L/32, SSM_B), 256, 0, stream>>>(rT, r, Dp, out);
}

// Round 4
// 312.266 us; speedup vs baseline: 1.4056x; 1.1031x over previous
//
#include <hip/hip_runtime.h>
#include <math.h>

#define SSM_N 64
#define SSM_H 1024
#define SSM_L 2048
#define SSM_B 8
#define FFTN 2048
#define NT 256
#define KFS 2052   // row stride (float2) for Kf, 2049 used

// XOR swizzle on float2 index: touches bits 0-3 only, so
//   PSWZ(a + 256q) = PSWZ(a) + 256q  and  PSWZ(a + 512q) = PSWZ(a) + 512q.
// Reads/radix-4 addressing hoist to one base; strided writes get <=4-way spread.
#define PSWZ(a) ((a) ^ (((a) >> 4) & 15))

typedef float f2 __attribute__((ext_vector_type(2)));
static __device__ __forceinline__ f2 mkf2(float a, float b){ f2 v; v.x = a; v.y = b; return v; }

// packed complex multiply: v_pk_mul + v_pk_fma
static __device__ __forceinline__ f2 cmul(f2 a, f2 b){
  return mkf2(-a.y, a.y) * mkf2(b.y, b.x) + mkf2(a.x, a.x) * b;
}
static __device__ __forceinline__ f2 cconj(f2 a){ return mkf2(a.x, -a.y); }

template<bool INV> static __device__ __forceinline__ f2 mul_mi(f2 a){
  return INV ? mkf2(-a.y, a.x) : mkf2(a.y, -a.x);
}
template<bool INV> static __device__ __forceinline__ f2 mul_w81(f2 a){
  const float r = 0.70710678118654752440f;
  return INV ? (r * mkf2(a.x - a.y, a.y + a.x)) : (r * mkf2(a.x + a.y, a.y - a.x));
}
template<bool INV> static __device__ __forceinline__ f2 mul_w83(f2 a){
  const float r = 0.70710678118654752440f;
  return INV ? (r * mkf2(-(a.x + a.y), a.x - a.y)) : (r * mkf2(a.y - a.x, -(a.x + a.y)));
}

// radix-8 butterfly + twiddled writes; x[0..7] in regs, t=thread, j=twiddle exp, base=write base
template<bool INV>
static __device__ __forceinline__ void bfly8_store(f2* __restrict__ dst, const f2* __restrict__ tw,
                                                   f2* x, int j, int base, int S)
{
  f2 t0=x[0]+x[4], t4=x[0]-x[4];
  f2 t1=x[1]+x[5], t5=x[1]-x[5];
  f2 t2=x[2]+x[6], t6=x[2]-x[6];
  f2 t3=x[3]+x[7], t7=x[3]-x[7];
  f2 b0=t0+t2, b2=t0-t2, b1=t1+t3, b3=t1-t3;
  f2 mb3 = mul_mi<INV>(b3);
  f2 y0=b0+b1, y4=b0-b1, y2=b2+mb3, y6=b2-mb3;
  f2 v1 = mul_w81<INV>(t5), v2 = mul_mi<INV>(t6), v3 = mul_w83<INV>(t7);
  f2 a0=t4+v2, a2=t4-v2, a1=v1+v3, a3=v1-v3;
  f2 ma3 = mul_mi<INV>(a3);
  f2 y1=a0+a1, y5=a0-a1, y3=a2+ma3, y7=a2-ma3;
  f2 w1 = tw[j];
  if (INV) w1.y = -w1.y;
  f2 w2 = cmul(w1,w1);
  f2 w3 = cmul(w2,w1);
  f2 w4 = cmul(w2,w2);
  f2 w5 = cmul(w3,w2);
  f2 w6 = cmul(w3,w3);
  f2 w7 = cmul(w4,w3);
  dst[PSWZ(base)]     = y0;
  dst[PSWZ(base+S)]   = cmul(y1,w1);
  dst[PSWZ(base+2*S)] = cmul(y2,w2);
  dst[PSWZ(base+3*S)] = cmul(y3,w3);
  dst[PSWZ(base+4*S)] = cmul(y4,w4);
  dst[PSWZ(base+5*S)] = cmul(y5,w5);
  dst[PSWZ(base+6*S)] = cmul(y6,w6);
  dst[PSWZ(base+7*S)] = cmul(y7,w7);
}

// first stage (S=1). ZTOP: logical top half (q>=4) is zero -> skip those reads.
template<bool INV, bool ZTOP>
static __device__ __forceinline__ void stage8_first(const f2* __restrict__ src, f2* __restrict__ dst,
                                                    const f2* __restrict__ tw, int t, int st)
{
  const f2* sp = src + st;
  f2 x[8];
  if (ZTOP) {
    #pragma unroll
    for (int q = 0; q < 4; ++q) { x[q] = sp[256*q]; x[q+4] = x[q]; }
    // with x[q+4]==x[q]: t_k = 2*x[k] is wrong -- must emulate x[q+4]=0:
    // handled by replacing sums: (x[q]+0, x[q]-0) -> both x[q]. So set:
    #pragma unroll
    for (int q = 0; q < 4; ++q) x[q+4] = mkf2(0.f, 0.f);
  } else {
    #pragma unroll
    for (int q = 0; q < 8; ++q) x[q] = sp[256*q];
  }
  bfly8_store<INV>(dst, tw, x, t, t*8, 1);
}

// middle stages S = 8 or 64
template<bool INV, int S>
static __device__ __forceinline__ void stage8_mid(const f2* __restrict__ src, f2* __restrict__ dst,
                                                  const f2* __restrict__ tw, int t, int st)
{
  const f2* sp = src + st;
  f2 x[8];
  #pragma unroll
  for (int q = 0; q < 8; ++q) x[q] = sp[256*q];
  int i = t & (S-1);
  int j = t - i;
  bfly8_store<INV>(dst, tw, x, j, i + j*8, S);
}

// final radix-4, span 512. HALFOUT: only logical [0,1024) needed.
template<bool INV, bool HALFOUT>
static __device__ __forceinline__ void stage4f(const f2* __restrict__ src, f2* __restrict__ dst, int st)
{
  #pragma unroll
  for (int hh = 0; hh < 2; ++hh) {
    const f2* sp = src + st + 256*hh;
    f2* wp = dst + st + 256*hh;
    f2 x0=sp[0], x1=sp[512], x2=sp[1024], x3=sp[1536];
    f2 a0=x0+x2, a2=x0-x2, a1=x1+x3, a3=x1-x3;
    f2 m = mul_mi<INV>(a3);
    wp[0]   = a0+a1;
    wp[512] = a2+m;
    if (!HALFOUT) {
      wp[1024] = a0-a1;
      wp[1536] = a2-m;
    }
  }
}

// 2048-pt FFT, swizzled layout; input A, result A, B scratch.
template<bool INV, bool ZTOP, bool HALFOUT>
static __device__ void fft2048(f2* A, f2* B, const f2* tw, int t, int st)
{
  __syncthreads();
  stage8_first<INV, ZTOP>(A, B, tw, t, st);
  __syncthreads();
  stage8_mid<INV, 8>(B, A, tw, t, st);
  __syncthreads();
  stage8_mid<INV, 64>(A, B, tw, t, st);
  __syncthreads();
  stage4f<INV, HALFOUT>(B, A, st);
  __syncthreads();
}

static __device__ __forceinline__ void init_tw(f2* tw, int t)
{
  float s, c;
  sincosf(-6.2831853071795864769f * (float)t / (float)FFTN, &s, &c);
  tw[t] = mkf2(c, s);   // exponents used are 0..248
}

// Stage 1a: cden (transposed (N,L)), f2 = 2/(1+z), fac = k10/(1+k11). fp64 internally.
__global__ __launch_bounds__(256) void kernel_cden(
    const float* __restrict__ B_re, const float* __restrict__ B_im,
    const float* __restrict__ P_re, const float* __restrict__ P_im,
    const float* __restrict__ Q_re, const float* __restrict__ Q_im,
    const float* __restrict__ diag_re, const float* __restrict__ diag_im,
    const float* __restrict__ step,
    f2* __restrict__ cdenT, f2* __restrict__ f2v, f2* __restrict__ facv)
{
  int l = blockIdx.x * blockDim.x + threadIdx.x;
  if (l >= SSM_L) return;
  double stepc = (double)step[0]; if (stepc < 1e-6) stepc = 1e-6;
  double ang = -2.0 * 3.14159265358979323846 * (double)l / (double)SSM_L;
  double zr = cos(ang), zi = sin(ang);
  double dr = 1.0 + zr, di = zi;
  double nr = 1.0 - zr, ni = -zi;
  double den = dr*dr + di*di;
  double i2s = 2.0 / stepc;
  double gr = i2s * (nr*dr + ni*di) / den;
  double gi = i2s * (ni*dr - nr*di) / den;
  f2v[l] = mkf2((float)(2.0*dr/den), (float)(-2.0*di/den));
  double k10r=0.0, k10i=0.0, k11r=0.0, k11i=0.0;
  for (int n = 0; n < SSM_N; ++n) {
    double ar = gr - (double)diag_re[n];
    double ai = gi - (double)diag_im[n];
    double d2 = ar*ar + ai*ai;
    double cr = ar/d2, ci = -ai/d2;
    cdenT[n*SSM_L + l] = mkf2((float)cr, (float)ci);
    double qr = (double)Q_re[n], qi = (double)Q_im[n];
    double br = (double)B_re[n], bi = (double)B_im[n];
    double pr = (double)P_re[n], pi = (double)P_im[n];
    double qbr = qr*br - qi*bi, qbi = qr*bi + qi*br;
    double qpr = qr*pr - qi*pi, qpi = qr*pi + qi*pr;
    k10r += qbr*cr - qbi*ci; k10i += qbr*ci + qbi*cr;
    k11r += qpr*cr - qpi*ci; k11i += qpr*ci + qpi*cr;
  }
  double er = 1.0 + k11r, ei = k11i;
  double ed = er*er + ei*ei;
  facv[l] = mkf2((float)((k10r*er + k10i*ei)/ed), (float)((k10i*er - k10r*ei)/ed));
}

// Stage 1b: 2 channels per block: contraction -> per h: at_roots -> ifft -> K
// -> rfft4096 (packed) -> Kf row.
__global__ __launch_bounds__(NT, 2) void kernel_khat(
    const float* __restrict__ C_re, const float* __restrict__ C_im,
    const float* __restrict__ B_re, const float* __restrict__ B_im,
    const float* __restrict__ P_re, const float* __restrict__ P_im,
    const f2* __restrict__ cdenT,
    const f2* __restrict__ f2v, const f2* __restrict__ facv,
    f2* __restrict__ Kf)
{
  __shared__ f2 bufA[FFTN];
  __shared__ f2 bufB[FFTN];
  __shared__ f2 tw[256];
  int t = threadIdx.x;
  int st = PSWZ(t);
  int h0 = blockIdx.x * 2;
  init_tw(tw, t);
  // stage CB/CP for both h into bufA[0..255] (dead after contraction)
  if (t < 128) {
    int h = h0 + (t >> 6), n = t & 63;
    f2 cc = mkf2(C_re[h*SSM_N + n], C_im[h*SSM_N + n]);
    bufA[t]       = cmul(cc, mkf2(B_re[n], B_im[n]));
    bufA[128 + t] = cmul(cc, mkf2(P_re[n], P_im[n]));
  }
  __syncthreads();
  f2 k00[2][8], k01[2][8];
  #pragma unroll
  for (int h = 0; h < 2; ++h)
    #pragma unroll
    for (int i = 0; i < 8; ++i) { k00[h][i] = mkf2(0.f,0.f); k01[h][i] = mkf2(0.f,0.f); }
  for (int n = 0; n < SSM_N; ++n) {
    f2 cd[8];
    #pragma unroll
    for (int i = 0; i < 8; ++i) cd[i] = cdenT[n*SSM_L + t + i*NT];
    #pragma unroll
    for (int h = 0; h < 2; ++h) {
      f2 cb = bufA[h*64 + n], cp = bufA[128 + h*64 + n];
      #pragma unroll
      for (int i = 0; i < 8; ++i) {
        k00[h][i] = k00[h][i] + cmul(cb, cd[i]);
        k01[h][i] = k01[h][i] + cmul(cp, cd[i]);
      }
    }
  }
  for (int h = 0; h < 2; ++h) {
    __syncthreads();   // prev readers of bufA done
    #pragma unroll
    for (int i = 0; i < 8; ++i) {
      int l = t + i*NT;
      bufA[PSWZ(l)] = cmul(f2v[l], k00[h][i] - cmul(k01[h][i], facv[l]));
    }
    fft2048<true, false, false>(bufA, bufB, tw, t, st);   // result bufA
    const float scale = 1.0f / (float)FFTN;
    #pragma unroll
    for (int i = 0; i < 4; ++i) {              // pack even/odd of K; top half stays unused (ZTOP)
      int j = t + i*NT;                        // j < 1024
      bufB[PSWZ(j)] = mkf2(bufA[PSWZ(2*j)].x * scale, bufA[PSWZ(2*j+1)].x * scale);
    }
    fft2048<false, true, false>(bufB, bufA, tw, t, st);   // result bufB
    f2* krow = Kf + (size_t)(h0 + h) * KFS;
    #pragma unroll
    for (int i = 0; i < 4; ++i) {
      int k = t + i*NT;
      if (k == 0) {
        f2 c0 = bufB[0];
        krow[0]       = mkf2(c0.x + c0.y, 0.f);
        krow[FFTN]    = mkf2(c0.x - c0.y, 0.f);
        krow[FFTN/2]  = cconj(bufB[PSWZ(FFTN/2)]);
      } else {
        int kk = FFTN - k;
        f2 Ck = bufB[PSWZ(k)], Ckk = bufB[PSWZ(kk)];
        f2 E = mkf2(0.5f*(Ck.x + Ckk.x), 0.5f*(Ck.y - Ckk.y));
        f2 O = mkf2(0.5f*(Ck.y + Ckk.y), 0.5f*(Ckk.x - Ck.x));
        float s, c;
        sincosf(-3.14159265358979f * (float)k / (float)FFTN, &s, &c);
        krow[k]  = E + cmul(mkf2(c, s), O);
        krow[kk] = cconj(E) + cmul(mkf2(-c, s), cconj(O));
      }
    }
  }
}

// (B,L,H) -> (B,H,L) tiled transpose
__global__ __launch_bounds__(256) void ktranspose(const float* __restrict__ src, float* __restrict__ dst)
{
  __shared__ float tile[32][33];
  int tx = threadIdx.x & 31, ty = threadIdx.x >> 5;
  int h0 = blockIdx.x * 32, l0 = blockIdx.y * 32, b = blockIdx.z;
  const float* s = src + ((size_t)b*SSM_L + l0)*SSM_H + h0;
  #pragma unroll
  for (int i = 0; i < 4; ++i) { int row = ty + i*8; tile[row][tx] = s[(size_t)row*SSM_H + tx]; }
  __syncthreads();
  float* d = dst + ((size_t)b*SSM_H + h0)*SSM_L + l0;
  #pragma unroll
  for (int i = 0; i < 4; ++i) { int row = ty + i*8; d[(size_t)row*SSM_L + tx] = tile[tx][row]; }
}

// Stage 2: per (b,h) row in rT: rfft4096 (packed) -> *Kf -> irfft4096, keep first L.
__global__ __launch_bounds__(NT, 4) void kernel_conv(float* __restrict__ rT, const f2* __restrict__ Kf)
{
  __shared__ f2 bufA[FFTN];
  __shared__ f2 bufB[FFTN];
  __shared__ f2 tw[256];
  int t = threadIdx.x;
  int st = PSWZ(t);
  int row = blockIdx.x;
  int h = row & (SSM_H - 1);
  init_tw(tw, t);
  float* rrow = rT + (size_t)row * SSM_L;
  const float4* r4 = (const float4*)rrow;
  #pragma unroll
  for (int i = 0; i < 2; ++i) {                  // 2048 reals -> lower 1024 packed float2
    int j2 = t + i*NT;                           // < 512
    float4 v = r4[j2];
    bufA[PSWZ(2*j2)]   = mkf2(v.x, v.y);
    bufA[PSWZ(2*j2+1)] = mkf2(v.z, v.w);
  }
  fft2048<false, true, false>(bufA, bufB, tw, t, st);   // spectrum in bufA
  const f2* krow = Kf + (size_t)h * KFS;
  #pragma unroll
  for (int i = 0; i < 4; ++i) {                  // unpack -> *Kf -> repack into bufB
    int k = t + i*NT;
    if (k == 0) {
      f2 c0 = bufA[0];
      float F0 = c0.x + c0.y, Fn = c0.x - c0.y;
      f2 K0 = krow[0], Kn = krow[FFTN];
      f2 G0 = F0 * K0;
      f2 Gn = Fn * Kn;
      f2 Xe = 0.5f * (G0 + Gn);
      f2 Xo = 0.5f * (G0 - Gn);
      bufB[0] = mkf2(Xe.x - Xo.y, Xe.y + Xo.x);
      f2 Gm = cmul(cconj(bufA[PSWZ(FFTN/2)]), krow[FFTN/2]);
      bufB[PSWZ(FFTN/2)] = cconj(Gm);
    } else {
      int kk = FFTN - k;
      f2 Ck = bufA[PSWZ(k)], Ckk = bufA[PSWZ(kk)];
      f2 E = mkf2(0.5f*(Ck.x + Ckk.x), 0.5f*(Ck.y - Ckk.y));
      f2 O = mkf2(0.5f*(Ck.y + Ckk.y), 0.5f*(Ckk.x - Ck.x));
      float s, c;
      sincosf(-3.14159265358979f * (float)k / (float)FFTN, &s, &c);
      f2 Fk  = E + cmul(mkf2(c, s), O);
      f2 Fkk = cconj(E) + cmul(mkf2(-c, s), cconj(O));
      f2 Gk  = cmul(Fk,  krow[k]);
      f2 Gkk = cmul(Fkk, krow[kk]);
      f2 Xe  = mkf2(0.5f*(Gk.x + Gkk.x), 0.5f*(Gk.y - Gkk.y));
      f2 Dd  = mkf2(0.5f*(Gk.x - Gkk.x), 0.5f*(Gk.y + Gkk.y));
      f2 Xo  = cmul(mkf2(c, -s), Dd);            // conj(w) * Dd
      bufB[PSWZ(k)] = mkf2(Xe.x - Xo.y, Xe.y + Xo.x);
      f2 Xe2 = mkf2(0.5f*(Gkk.x + Gk.x), 0.5f*(Gkk.y - Gk.y));
      f2 Dd2 = mkf2(0.5f*(Gkk.x - Gk.x), 0.5f*(Gkk.y + Gk.y));
      f2 Xo2 = cmul(mkf2(-c, -s), Dd2);          // -w * Dd2
      bufB[PSWZ(kk)] = mkf2(Xe2.x - Xo2.y, Xe2.y + Xo2.x);
    }
  }
  fft2048<true, false, true>(bufB, bufA, tw, t, st);    // result (lower half) in bufB
  const float sc = 1.0f / (float)FFTN;
  float4* w4 = (float4*)rrow;
  #pragma unroll
  for (int i = 0; i < 2; ++i) {
    int j2 = t + i*NT;                           // < 512 -> logical idx < 1024
    f2 z0 = bufB[PSWZ(2*j2)], z1 = bufB[PSWZ(2*j2+1)];
    w4[j2] = make_float4(z0.x*sc, z0.y*sc, z1.x*sc, z1.y*sc);
  }
}

// (B,H,L) -> (B,L,H) transpose fused with + D*r and exact GELU
__global__ __launch_bounds__(256) void ktback(const float* __restrict__ yT, const float* __restrict__ r,
                                              const float* __restrict__ Dp, float* __restrict__ out)
{
  __shared__ float tile[32][33];
  int tx = threadIdx.x & 31, ty = threadIdx.x >> 5;
  int h0 = blockIdx.x * 32, l0 = blockIdx.y * 32, b = blockIdx.z;
  const float* s = yT + ((size_t)b*SSM_H + h0)*SSM_L + l0;
  #pragma unroll
  for (int i = 0; i < 4; ++i) { int row = ty + i*8; tile[row][tx] = s[(size_t)row*SSM_L + tx]; }
  __syncthreads();
  float Dv = Dp[0];
  float* o = out + ((size_t)b*SSM_L + l0)*SSM_H + h0;
  const float* rr = r + ((size_t)b*SSM_L + l0)*SSM_H + h0;
  #pragma unroll
  for (int i = 0; i < 4; ++i) {
    int row = ty + i*8;
    float x = tile[tx][row] + Dv * rr[(size_t)row*SSM_H + tx];
    float g = 0.5f * x * (1.0f + erff(x * 0.70710678118654752f));
    o[(size_t)row*SSM_H + tx] = g;
  }
}

extern "C" void kernel_launch(void* const* d_in, const int* in_sizes, int n_in,
                              void* d_out, int out_size, void* d_ws, size_t ws_size,
                              hipStream_t stream)
{
  const float* r       = (const float*)d_in[0];
  const float* B_re    = (const float*)d_in[1];
  const float* B_im    = (const float*)d_in[2];
  const float* C_re    = (const float*)d_in[3];
  const float* C_im    = (const float*)d_in[4];
  const float* P_re    = (const float*)d_in[5];
  const float* P_im    = (const float*)d_in[6];
  const float* Q_re    = (const float*)d_in[7];
  const float* Q_im    = (const float*)d_in[8];
  const float* diag_re = (const float*)d_in[9];
  const float* diag_im = (const float*)d_in[10];
  const float* step    = (const float*)d_in[11];
  const float* Dp      = (const float*)d_in[12];
  float* out = (float*)d_out;

  char* p = (char*)d_ws;
  float* rT  = (float*)p; p += (size_t)SSM_B*SSM_H*SSM_L*sizeof(float);   // 64 MiB
  f2* cdenT  = (f2*)p;    p += (size_t)SSM_N*SSM_L*sizeof(f2);            // 1 MiB
  f2* f2v    = (f2*)p;    p += (size_t)SSM_L*sizeof(f2);
  f2* facv   = (f2*)p;    p += (size_t)SSM_L*sizeof(f2);
  f2* Kf     = (f2*)p;    p += (size_t)SSM_H*KFS*sizeof(f2);              // ~16.8 MiB

  kernel_cden<<<SSM_L/NT, NT, 0, stream>>>(B_re, B_im, P_re, P_im, Q_re, Q_im,
                                           diag_re, diag_im, step, cdenT, f2v, facv);
  kernel_khat<<<SSM_H/2, NT, 0, stream>>>(C_re, C_im, B_re, B_im, P_re, P_im,
                                          cdenT, f2v, facv, Kf);
  ktranspose<<<dim3(SSM_H/32, SSM_L/32, SSM_B), 256, 0, stream>>>(r, rT);
  kernel_conv<<<SSM_B*SSM_H, NT, 0, stream>>>(rT, Kf);
  ktback<<<dim3(SSM_H/32, SSM_L/32, SSM_B), 256, 0, stream>>>(rT, r, Dp, out);
}

// Round 5
// 287.321 us; speedup vs baseline: 1.5277x; 1.0868x over previous
//
#include <hip/hip_runtime.h>
#include <math.h>

#define SSM_N 64
#define SSM_H 1024
#define SSM_L 2048
#define SSM_B 8
#define FFTN 2048
#define NT 256
#define KFS 2052   // row stride (f2) for Kf, 2049 used

// XOR swizzle on float2 index: touches bits 0-3 only, so PSWZ(a+256q)=PSWZ(a)+256q.
#define PSWZ(a) ((a) ^ (((a) >> 4) & 15))

typedef float f2 __attribute__((ext_vector_type(2)));
static __device__ __forceinline__ f2 mkf2(float a, float b){ f2 v; v.x = a; v.y = b; return v; }

static __device__ __forceinline__ f2 cmul(f2 a, f2 b){
  return mkf2(-a.y, a.y) * mkf2(b.y, b.x) + mkf2(a.x, a.x) * b;
}
static __device__ __forceinline__ f2 cconj(f2 a){ return mkf2(a.x, -a.y); }

template<bool INV> static __device__ __forceinline__ f2 mul_mi(f2 a){
  return INV ? mkf2(-a.y, a.x) : mkf2(a.y, -a.x);
}
template<bool INV> static __device__ __forceinline__ f2 mul_w81(f2 a){
  const float r = 0.70710678118654752440f;
  return INV ? (r * mkf2(a.x - a.y, a.y + a.x)) : (r * mkf2(a.x + a.y, a.y - a.x));
}
template<bool INV> static __device__ __forceinline__ f2 mul_w83(f2 a){
  const float r = 0.70710678118654752440f;
  return INV ? (r * mkf2(-(a.x + a.y), a.x - a.y)) : (r * mkf2(a.y - a.x, -(a.x + a.y)));
}

// exp(-i*pi*k/8) table (cos, -sin)
#define W8C0 1.f
#define W8S0 0.f
#define W8C1 0.92387953251f
#define W8S1 (-0.38268343236f)
#define W8C2 0.70710678119f
#define W8S2 (-0.70710678119f)
#define W8C3 0.38268343236f
#define W8S3 (-0.92387953251f)
#define W8C4 0.f
#define W8S4 (-1.f)
#define W8C5 (-0.38268343236f)
#define W8S5 (-0.92387953251f)
#define W8C6 (-0.70710678119f)
#define W8S6 (-0.70710678119f)
#define W8C7 (-0.92387953251f)
#define W8S7 (-0.38268343236f)

template<bool INV>
static __device__ __forceinline__ void bfly8_store(f2* __restrict__ dst, const f2* __restrict__ tw,
                                                   f2* x, int j, int base, int S)
{
  f2 t0=x[0]+x[4], t4=x[0]-x[4];
  f2 t1=x[1]+x[5], t5=x[1]-x[5];
  f2 t2=x[2]+x[6], t6=x[2]-x[6];
  f2 t3=x[3]+x[7], t7=x[3]-x[7];
  f2 b0=t0+t2, b2=t0-t2, b1=t1+t3, b3=t1-t3;
  f2 mb3 = mul_mi<INV>(b3);
  f2 y0=b0+b1, y4=b0-b1, y2=b2+mb3, y6=b2-mb3;
  f2 v1 = mul_w81<INV>(t5), v2 = mul_mi<INV>(t6), v3 = mul_w83<INV>(t7);
  f2 a0=t4+v2, a2=t4-v2, a1=v1+v3, a3=v1-v3;
  f2 ma3 = mul_mi<INV>(a3);
  f2 y1=a0+a1, y5=a0-a1, y3=a2+ma3, y7=a2-ma3;
  f2 w1 = tw[j];
  if (INV) w1.y = -w1.y;
  f2 w2 = cmul(w1,w1);
  f2 w3 = cmul(w2,w1);
  f2 w4 = cmul(w2,w2);
  f2 w5 = cmul(w3,w2);
  f2 w6 = cmul(w3,w3);
  f2 w7 = cmul(w4,w3);
  dst[PSWZ(base)]     = y0;
  dst[PSWZ(base+S)]   = cmul(y1,w1);
  dst[PSWZ(base+2*S)] = cmul(y2,w2);
  dst[PSWZ(base+3*S)] = cmul(y3,w3);
  dst[PSWZ(base+4*S)] = cmul(y4,w4);
  dst[PSWZ(base+5*S)] = cmul(y5,w5);
  dst[PSWZ(base+6*S)] = cmul(y6,w6);
  dst[PSWZ(base+7*S)] = cmul(y7,w7);
}

template<bool INV, bool ZTOP>
static __device__ __forceinline__ void stage8_first(const f2* __restrict__ src, f2* __restrict__ dst,
                                                    const f2* __restrict__ tw, int t, int st)
{
  const f2* sp = src + st;
  f2 x[8];
  if (ZTOP) {
    #pragma unroll
    for (int q = 0; q < 4; ++q) { x[q] = sp[256*q]; x[q+4] = mkf2(0.f, 0.f); }
  } else {
    #pragma unroll
    for (int q = 0; q < 8; ++q) x[q] = sp[256*q];
  }
  bfly8_store<INV>(dst, tw, x, t, t*8, 1);
}

template<bool INV, int S>
static __device__ __forceinline__ void stage8_mid(const f2* __restrict__ src, f2* __restrict__ dst,
                                                  const f2* __restrict__ tw, int t, int st)
{
  const f2* sp = src + st;
  f2 x[8];
  #pragma unroll
  for (int q = 0; q < 8; ++q) x[q] = sp[256*q];
  int i = t & (S-1);
  int j = t - i;
  bfly8_store<INV>(dst, tw, x, j, i + j*8, S);
}

template<bool INV, bool HALFOUT>
static __device__ __forceinline__ void stage4f(const f2* __restrict__ src, f2* __restrict__ dst, int st)
{
  #pragma unroll
  for (int hh = 0; hh < 2; ++hh) {
    const f2* sp = src + st + 256*hh;
    f2* wp = dst + st + 256*hh;
    f2 x0=sp[0], x1=sp[512], x2=sp[1024], x3=sp[1536];
    f2 a0=x0+x2, a2=x0-x2, a1=x1+x3, a3=x1-x3;
    f2 m = mul_mi<INV>(a3);
    wp[0]   = a0+a1;
    wp[512] = a2+m;
    if (!HALFOUT) {
      wp[1024] = a0-a1;
      wp[1536] = a2-m;
    }
  }
}

// 2048-pt FFT, swizzled layout; input A, result A, B scratch.
template<bool INV, bool ZTOP, bool HALFOUT>
static __device__ void fft2048(f2* A, f2* B, const f2* tw, int t, int st)
{
  __syncthreads();
  stage8_first<INV, ZTOP>(A, B, tw, t, st);
  __syncthreads();
  stage8_mid<INV, 8>(B, A, tw, t, st);
  __syncthreads();
  stage8_mid<INV, 64>(A, B, tw, t, st);
  __syncthreads();
  stage4f<INV, HALFOUT>(B, A, st);
  __syncthreads();
}

static __device__ __forceinline__ void init_tw(f2* tw, int t)
{
  float s, c;
  sincosf(-6.2831853071795864769f * (float)t / (float)FFTN, &s, &c);
  tw[t] = mkf2(c, s);   // exponents used are 0..248
}

// Stage 1a: cden (transposed (N,L)), f2 = 2/(1+z), fac = k10/(1+k11). fp64 internally.
// 8 lanes per l, shfl-reduced; 64 blocks.
__global__ __launch_bounds__(256) void kernel_cden(
    const float* __restrict__ B_re, const float* __restrict__ B_im,
    const float* __restrict__ P_re, const float* __restrict__ P_im,
    const float* __restrict__ Q_re, const float* __restrict__ Q_im,
    const float* __restrict__ diag_re, const float* __restrict__ diag_im,
    const float* __restrict__ step,
    f2* __restrict__ cdenT, f2* __restrict__ f2v, f2* __restrict__ facv)
{
  int gid = blockIdx.x * blockDim.x + threadIdx.x;   // 16384 threads
  int l = gid >> 3, s = gid & 7;
  double stepc = (double)step[0]; if (stepc < 1e-6) stepc = 1e-6;
  double ang = -2.0 * 3.14159265358979323846 * (double)l / (double)SSM_L;
  double zr = cos(ang), zi = sin(ang);
  double dr = 1.0 + zr, di = zi;
  double nr = 1.0 - zr, ni = -zi;
  double den = dr*dr + di*di;
  double i2s = 2.0 / stepc;
  double gr = i2s * (nr*dr + ni*di) / den;
  double gi = i2s * (ni*dr - nr*di) / den;
  double k10r=0.0, k10i=0.0, k11r=0.0, k11i=0.0;
  #pragma unroll
  for (int q = 0; q < 8; ++q) {
    int n = s*8 + q;
    double ar = gr - (double)diag_re[n];
    double ai = gi - (double)diag_im[n];
    double d2 = ar*ar + ai*ai;
    double cr = ar/d2, ci = -ai/d2;
    cdenT[n*SSM_L + l] = mkf2((float)cr, (float)ci);
    double qr = (double)Q_re[n], qi = (double)Q_im[n];
    double br = (double)B_re[n], bi = (double)B_im[n];
    double pr = (double)P_re[n], pi = (double)P_im[n];
    double qbr = qr*br - qi*bi, qbi = qr*bi + qi*br;
    double qpr = qr*pr - qi*pi, qpi = qr*pi + qi*pr;
    k10r += qbr*cr - qbi*ci; k10i += qbr*ci + qbi*cr;
    k11r += qpr*cr - qpi*ci; k11i += qpr*ci + qpi*cr;
  }
  #pragma unroll
  for (int off = 1; off < 8; off <<= 1) {
    k10r += __shfl_xor(k10r, off);
    k10i += __shfl_xor(k10i, off);
    k11r += __shfl_xor(k11r, off);
    k11i += __shfl_xor(k11i, off);
  }
  if (s == 0) {
    f2v[l] = mkf2((float)(2.0*dr/den), (float)(-2.0*di/den));
    double er = 1.0 + k11r, ei = k11i;
    double ed = er*er + ei*ei;
    facv[l] = mkf2((float)((k10r*er + k10i*ei)/ed), (float)((k10i*er - k10r*ei)/ed));
  }
}

// Stage 1b-1: contraction only -> at_roots (H,L). 2 channels per block, 512 blocks.
__global__ __launch_bounds__(NT, 2) void kgemm(
    const float* __restrict__ C_re, const float* __restrict__ C_im,
    const float* __restrict__ B_re, const float* __restrict__ B_im,
    const float* __restrict__ P_re, const float* __restrict__ P_im,
    const f2* __restrict__ cdenT, const f2* __restrict__ f2v, const f2* __restrict__ facv,
    f2* __restrict__ atr)
{
  __shared__ f2 cbs[256];
  int t = threadIdx.x;
  int h0 = blockIdx.x * 2;
  if (t < 128) {
    int h = h0 + (t >> 6), n = t & 63;
    f2 cc = mkf2(C_re[h*SSM_N + n], C_im[h*SSM_N + n]);
    cbs[t]       = cmul(cc, mkf2(B_re[n], B_im[n]));
    cbs[128 + t] = cmul(cc, mkf2(P_re[n], P_im[n]));
  }
  __syncthreads();
  f2 k00[2][8], k01[2][8];
  #pragma unroll
  for (int h = 0; h < 2; ++h)
    #pragma unroll
    for (int i = 0; i < 8; ++i) { k00[h][i] = mkf2(0.f,0.f); k01[h][i] = mkf2(0.f,0.f); }
  for (int n = 0; n < SSM_N; ++n) {
    f2 cd[8];
    #pragma unroll
    for (int i = 0; i < 8; ++i) cd[i] = cdenT[n*SSM_L + t + i*NT];
    #pragma unroll
    for (int h = 0; h < 2; ++h) {
      f2 cb = cbs[h*64 + n], cp = cbs[128 + h*64 + n];
      #pragma unroll
      for (int i = 0; i < 8; ++i) {
        k00[h][i] = k00[h][i] + cmul(cb, cd[i]);
        k01[h][i] = k01[h][i] + cmul(cp, cd[i]);
      }
    }
  }
  #pragma unroll
  for (int h = 0; h < 2; ++h) {
    f2* arow = atr + (size_t)(h0 + h) * SSM_L;
    #pragma unroll
    for (int i = 0; i < 8; ++i) {
      int l = t + i*NT;
      arow[l] = cmul(f2v[l], k00[h][i] - cmul(k01[h][i], facv[l]));
    }
  }
}

// Stage 1b-2: per h: Kf even bins = sym(at_roots); K = Re(ifft(at_roots))/N;
// Kf odd bins = FFT(K * exp(-i*pi*n/2048)).  1024 blocks.
__global__ __launch_bounds__(NT, 4) void kfft(const f2* __restrict__ atr, f2* __restrict__ Kf)
{
  __shared__ f2 bufA[FFTN];
  __shared__ f2 bufB[FFTN];
  __shared__ f2 tw[256];
  int t = threadIdx.x;
  int st = PSWZ(t);
  int h = blockIdx.x;
  init_tw(tw, t);
  const f2* arow = atr + (size_t)h * SSM_L;
  #pragma unroll
  for (int i = 0; i < 8; ++i) {
    int n = t + i*NT;
    bufA[PSWZ(n)] = arow[n];
  }
  fft2048<true, false, false>(bufA, bufB, tw, t, st);   // z in bufA (unscaled)
  // K*c into bufB
  float sb, cb;
  sincosf(-3.14159265358979f * (float)t / (float)FFTN, &sb, &cb);
  f2 base = mkf2(cb, sb);
  const float scale = 1.0f / (float)FFTN;
  {
    const float Wc[8] = {W8C0,W8C1,W8C2,W8C3,W8C4,W8C5,W8C6,W8C7};
    const float Ws[8] = {W8S0,W8S1,W8S2,W8S3,W8S4,W8S5,W8S6,W8S7};
    #pragma unroll
    for (int i = 0; i < 8; ++i) {
      int n = t + i*NT;
      float K = bufA[PSWZ(n)].x * scale;
      f2 c = cmul(base, mkf2(Wc[i], Ws[i]));
      bufB[PSWZ(n)] = K * c;
    }
  }
  fft2048<false, false, true>(bufB, bufA, tw, t, st);   // odd bins (lower half) in bufB
  f2* krow = Kf + (size_t)h * KFS;
  #pragma unroll
  for (int i = 0; i < 4; ++i) {                         // odd bins 2m+1, m<1024
    int m = t + i*NT;
    krow[2*m+1] = bufB[PSWZ(m)];
  }
  #pragma unroll
  for (int i = 0; i < 4; ++i) {                         // even bins 2m from at_roots
    int m = t + i*NT;
    if (m == 0) {
      krow[0]    = mkf2(arow[0].x, 0.f);
      krow[FFTN] = mkf2(arow[FFTN/2].x, 0.f);
    } else {
      krow[2*m] = 0.5f * (arow[m] + cconj(arow[FFTN - m]));
    }
  }
}

// (B,L,H) -> (B,H,L) transpose, 64x64 float4 tiles
__global__ __launch_bounds__(256) void ktranspose(const float* __restrict__ src, float* __restrict__ dst)
{
  __shared__ float til[64][65];
  int t = threadIdx.x, tx = t & 15, ty = t >> 4;
  int h0 = blockIdx.x * 64, l0 = blockIdx.y * 64, b = blockIdx.z;
  const float4* s4 = (const float4*)(src + ((size_t)b*SSM_L + l0)*SSM_H + h0);
  #pragma unroll
  for (int i = 0; i < 4; ++i) {
    int lr = ty + 16*i;
    float4 v = s4[(size_t)lr*(SSM_H/4) + tx];
    til[lr][4*tx+0]=v.x; til[lr][4*tx+1]=v.y; til[lr][4*tx+2]=v.z; til[lr][4*tx+3]=v.w;
  }
  __syncthreads();
  float4* d4 = (float4*)(dst + ((size_t)b*SSM_H + h0)*SSM_L + l0);
  #pragma unroll
  for (int i = 0; i < 4; ++i) {
    int hr = ty + 16*i;
    float4 w;
    w.x = til[4*tx+0][hr]; w.y = til[4*tx+1][hr];
    w.z = til[4*tx+2][hr]; w.w = til[4*tx+3][hr];
    d4[(size_t)hr*(SSM_L/4) + tx] = w;
  }
}

// Stage 2: per (b,h) row in rT: rfft4096 (packed) -> *Kf -> irfft4096 + D*r, keep first L.
__global__ __launch_bounds__(NT, 4) void kernel_conv(float* __restrict__ rT, const f2* __restrict__ Kf,
                                                     const float* __restrict__ Dp)
{
  __shared__ f2 bufA[FFTN];
  __shared__ f2 bufB[FFTN];
  __shared__ f2 tw[256];
  int t = threadIdx.x;
  int st = PSWZ(t);
  int row = blockIdx.x;
  int h = row & (SSM_H - 1);
  float Dv = Dp[0];
  init_tw(tw, t);
  float* rrow = rT + (size_t)row * SSM_L;
  const float4* r4 = (const float4*)rrow;
  float4 vin[2];
  #pragma unroll
  for (int i = 0; i < 2; ++i) {                  // 2048 reals -> lower 1024 packed f2
    int j2 = t + i*NT;                           // < 512
    vin[i] = r4[j2];
    bufA[PSWZ(2*j2)]   = mkf2(vin[i].x, vin[i].y);
    bufA[PSWZ(2*j2+1)] = mkf2(vin[i].z, vin[i].w);
  }
  fft2048<false, true, false>(bufA, bufB, tw, t, st);   // spectrum in bufA
  const f2* krow = Kf + (size_t)h * KFS;
  float sb, cb;
  sincosf(-3.14159265358979f * (float)t / (float)FFTN, &sb, &cb);
  f2 base = mkf2(cb, sb);
  {
    const float Wc[4] = {W8C0,W8C1,W8C2,W8C3};
    const float Ws[4] = {W8S0,W8S1,W8S2,W8S3};
    #pragma unroll
    for (int i = 0; i < 4; ++i) {                // unpack -> *Kf -> repack into bufB
      int k = t + i*NT;
      f2 w = cmul(base, mkf2(Wc[i], Ws[i]));     // exp(-i*pi*k/2048)
      float c = w.x, s = w.y;
      if (k == 0) {
        f2 c0 = bufA[0];
        float F0 = c0.x + c0.y, Fn = c0.x - c0.y;
        f2 K0 = krow[0], Kn = krow[FFTN];
        f2 G0 = F0 * K0;
        f2 Gn = Fn * Kn;
        f2 Xe = 0.5f * (G0 + Gn);
        f2 Xo = 0.5f * (G0 - Gn);
        bufB[0] = mkf2(Xe.x - Xo.y, Xe.y + Xo.x);
        f2 Gm = cmul(cconj(bufA[PSWZ(FFTN/2)]), krow[FFTN/2]);
        bufB[PSWZ(FFTN/2)] = cconj(Gm);
      } else {
        int kk = FFTN - k;
        f2 Ck = bufA[PSWZ(k)], Ckk = bufA[PSWZ(kk)];
        f2 E = mkf2(0.5f*(Ck.x + Ckk.x), 0.5f*(Ck.y - Ckk.y));
        f2 O = mkf2(0.5f*(Ck.y + Ckk.y), 0.5f*(Ckk.x - Ck.x));
        f2 Fk  = E + cmul(mkf2(c, s), O);
        f2 Fkk = cconj(E) + cmul(mkf2(-c, s), cconj(O));
        f2 Gk  = cmul(Fk,  krow[k]);
        f2 Gkk = cmul(Fkk, krow[kk]);
        f2 Xe  = mkf2(0.5f*(Gk.x + Gkk.x), 0.5f*(Gk.y - Gkk.y));
        f2 Dd  = mkf2(0.5f*(Gk.x - Gkk.x), 0.5f*(Gk.y + Gkk.y));
        f2 Xo  = cmul(mkf2(c, -s), Dd);          // conj(w) * Dd
        bufB[PSWZ(k)] = mkf2(Xe.x - Xo.y, Xe.y + Xo.x);
        f2 Xe2 = mkf2(0.5f*(Gkk.x + Gk.x), 0.5f*(Gkk.y - Gk.y));
        f2 Dd2 = mkf2(0.5f*(Gkk.x - Gk.x), 0.5f*(Gkk.y + Gk.y));
        f2 Xo2 = cmul(mkf2(-c, -s), Dd2);        // -w * Dd2
        bufB[PSWZ(kk)] = mkf2(Xe2.x - Xo2.y, Xe2.y + Xo2.x);
      }
    }
  }
  fft2048<true, false, true>(bufB, bufA, tw, t, st);    // result (lower half) in bufB
  const float sc = 1.0f / (float)FFTN;
  float4* w4 = (float4*)rrow;
  #pragma unroll
  for (int i = 0; i < 2; ++i) {
    int j2 = t + i*NT;
    f2 z0 = bufB[PSWZ(2*j2)], z1 = bufB[PSWZ(2*j2+1)];
    w4[j2] = make_float4(z0.x*sc + Dv*vin[i].x, z0.y*sc + Dv*vin[i].y,
                         z1.x*sc + Dv*vin[i].z, z1.y*sc + Dv*vin[i].w);
  }
}

// (B,H,L) -> (B,L,H) transpose + exact GELU, 64x64 float4 tiles
__global__ __launch_bounds__(256) void ktback(const float* __restrict__ yT, float* __restrict__ out)
{
  __shared__ float til[64][65];
  int t = threadIdx.x, tx = t & 15, ty = t >> 4;
  int h0 = blockIdx.x * 64, l0 = blockIdx.y * 64, b = blockIdx.z;
  const float4* s4 = (const float4*)(yT + ((size_t)b*SSM_H + h0)*SSM_L + l0);
  #pragma unroll
  for (int i = 0; i < 4; ++i) {
    int hr = ty + 16*i;
    float4 v = s4[(size_t)hr*(SSM_L/4) + tx];
    til[hr][4*tx+0]=v.x; til[hr][4*tx+1]=v.y; til[hr][4*tx+2]=v.z; til[hr][4*tx+3]=v.w;
  }
  __syncthreads();
  float4* d4 = (float4*)(out + ((size_t)b*SSM_L + l0)*SSM_H + h0);
  #pragma unroll
  for (int i = 0; i < 4; ++i) {
    int lr = ty + 16*i;
    float4 w;
    float x0 = til[4*tx+0][lr], x1 = til[4*tx+1][lr];
    float x2 = til[4*tx+2][lr], x3 = til[4*tx+3][lr];
    w.x = 0.5f * x0 * (1.0f + erff(x0 * 0.70710678118654752f));
    w.y = 0.5f * x1 * (1.0f + erff(x1 * 0.70710678118654752f));
    w.z = 0.5f * x2 * (1.0f + erff(x2 * 0.70710678118654752f));
    w.w = 0.5f * x3 * (1.0f + erff(x3 * 0.70710678118654752f));
    d4[(size_t)lr*(SSM_H/4) + tx] = w;
  }
}

extern "C" void kernel_launch(void* const* d_in, const int* in_sizes, int n_in,
                              void* d_out, int out_size, void* d_ws, size_t ws_size,
                              hipStream_t stream)
{
  const float* r       = (const float*)d_in[0];
  const float* B_re    = (const float*)d_in[1];
  const float* B_im    = (const float*)d_in[2];
  const float* C_re    = (const float*)d_in[3];
  const float* C_im    = (const float*)d_in[4];
  const float* P_re    = (const float*)d_in[5];
  const float* P_im    = (const float*)d_in[6];
  const float* Q_re    = (const float*)d_in[7];
  const float* Q_im    = (const float*)d_in[8];
  const float* diag_re = (const float*)d_in[9];
  const float* diag_im = (const float*)d_in[10];
  const float* step    = (const float*)d_in[11];
  const float* Dp      = (const float*)d_in[12];
  float* out = (float*)d_out;

  char* p = (char*)d_ws;
  float* rT  = (float*)p; p += (size_t)SSM_B*SSM_H*SSM_L*sizeof(float);   // 64 MiB
  f2* cdenT  = (f2*)p;    p += (size_t)SSM_N*SSM_L*sizeof(f2);            // 1 MiB
  f2* f2v    = (f2*)p;    p += (size_t)SSM_L*sizeof(f2);
  f2* facv   = (f2*)p;    p += (size_t)SSM_L*sizeof(f2);
  f2* Kf     = (f2*)p;    p += (size_t)SSM_H*KFS*sizeof(f2);              // ~16.8 MiB
  // at_roots aliases rT: dead before ktranspose writes rT
  f2* atr = (f2*)rT;                                                       // 16 MiB

  kernel_cden<<<SSM_L*8/NT, NT, 0, stream>>>(B_re, B_im, P_re, P_im, Q_re, Q_im,
                                             diag_re, diag_im, step, cdenT, f2v, facv);
  kgemm<<<SSM_H/2, NT, 0, stream>>>(C_re, C_im, B_re, B_im, P_re, P_im,
                                    cdenT, f2v, facv, atr);
  kfft<<<SSM_H, NT, 0, stream>>>(atr, Kf);
  ktranspose<<<dim3(SSM_H/64, SSM_L/64, SSM_B), 256, 0, stream>>>(r, rT);
  kernel_conv<<<SSM_B*SSM_H, NT, 0, stream>>>(rT, Kf, Dp);
  ktback<<<dim3(SSM_H/64, SSM_L/64, SSM_B), 256, 0, stream>>>(rT, out);
}